// Round 7
// baseline (1738.291 us; speedup 1.0000x reference)
//
#include <hip/hip_runtime.h>
#include <hip/hip_fp16.h>

#define TB 256
#define CHUNK 2048
#define NBK 512   // bucket array capacity (actual buckets = cdiv(M,256) <= 512)

// ---------------- index-width detection (int32 vs int64 src/dst) -------------
__global__ void detect_idx_kernel(const int* __restrict__ s32, const int* __restrict__ d32,
                                  int nE, int* __restrict__ flag) {
    __shared__ int nz;
    if (threadIdx.x == 0) nz = 0;
    __syncthreads();
    int n = nE < 2048 ? nE : 2048;
    int local = 0;
    for (int i = threadIdx.x; i < n; i += blockDim.x) {
        if (s32[2 * i + 1] != 0 || d32[2 * i + 1] != 0) local = 1;
    }
    if (local) atomicOr(&nz, 1);
    __syncthreads();
    if (threadIdx.x == 0) *flag = (nz == 0) ? 1 : 0;   // 1 => indices are int64
}

__device__ __forceinline__ int load_idx(const void* p, int e, int is64) {
    return is64 ? (int)((const long long*)p)[e] : ((const int*)p)[e];
}

// ---------------- CSR build --------------------------------------------------
// degree histogram + coarse bucket histogram (bucket = dst >> 8)
__global__ void hist2_kernel(const void* __restrict__ dst, const int* __restrict__ flag,
                             int* __restrict__ deg, int* __restrict__ hb, int nE) {
    int t = blockIdx.x * blockDim.x + threadIdx.x;
    if (t >= nE) return;
    int d = load_idx(dst, t, *flag);
    atomicAdd(&deg[d], 1);
    atomicAdd(&hb[d >> 8], 1);
}

// stage A: per-chunk sums (CHUNK=2048 elems per 256-thread block, 8/thread)
__global__ __launch_bounds__(TB) void bsum_kernel(const int* __restrict__ deg,
                                                  int* __restrict__ bsum, int M) {
    const int tid = threadIdx.x;
    const int base = blockIdx.x * CHUNK + tid * 8;
    int s = 0;
    if (base + 8 <= M) {
        int4 a = *(const int4*)(deg + base);
        int4 c = *(const int4*)(deg + base + 4);
        s = a.x + a.y + a.z + a.w + c.x + c.y + c.z + c.w;
    } else {
        for (int i = 0; i < 8; ++i) if (base + i < M) s += deg[base + i];
    }
    #pragma unroll
    for (int off = 1; off < 64; off <<= 1) s += __shfl_xor(s, off);
    __shared__ int wsum[4];
    const int lane = tid & 63, wv = tid >> 6;
    if (lane == 0) wsum[wv] = s;
    __syncthreads();
    if (tid == 0) bsum[blockIdx.x] = wsum[0] + wsum[1] + wsum[2] + wsum[3];
}

// stage B: one wave exclusive-scans chunk sums (nB <= 64), writes rowptr[M]
__global__ void topscan_kernel(const int* __restrict__ bsum, int* __restrict__ boff,
                               int* __restrict__ rowptr, int nB, int M) {
    const int tid = threadIdx.x;   // 64 threads
    int v = (tid < nB) ? bsum[tid] : 0;
    int x = v;
    #pragma unroll
    for (int off = 1; off < 64; off <<= 1) {
        int y = __shfl_up(x, off);
        if (tid >= off) x += y;
    }
    if (tid < nB) boff[tid] = x - v;
    if (tid == 63) rowptr[M] = x;
}

// stage C: chunk-local exclusive scan + chunk offset -> rowptr and cursor
__global__ __launch_bounds__(TB) void scan_chunk_kernel(
        const int* __restrict__ deg, const int* __restrict__ boff,
        int* __restrict__ rowptr, int* __restrict__ cursor, int M) {
    const int tid = threadIdx.x;
    const int base = blockIdx.x * CHUNK + tid * 8;
    int v[8];
    if (base + 8 <= M) {
        int4 a = *(const int4*)(deg + base);
        int4 c = *(const int4*)(deg + base + 4);
        v[0] = a.x; v[1] = a.y; v[2] = a.z; v[3] = a.w;
        v[4] = c.x; v[5] = c.y; v[6] = c.z; v[7] = c.w;
    } else {
        #pragma unroll
        for (int i = 0; i < 8; ++i) v[i] = (base + i < M) ? deg[base + i] : 0;
    }
    int tsum = 0;
    #pragma unroll
    for (int i = 0; i < 8; ++i) tsum += v[i];
    const int lane = tid & 63, wv = tid >> 6;
    int x = tsum;
    #pragma unroll
    for (int off = 1; off < 64; off <<= 1) {
        int y = __shfl_up(x, off);
        if (lane >= off) x += y;
    }
    __shared__ int wsum[4];
    if (lane == 63) wsum[wv] = x;
    __syncthreads();
    int wbase = 0;
    #pragma unroll
    for (int w = 0; w < 4; ++w) if (w < wv) wbase += wsum[w];
    int run = boff[blockIdx.x] + wbase + (x - tsum);
    #pragma unroll
    for (int i = 0; i < 8; ++i) {
        int idx = base + i;
        if (idx < M) { rowptr[idx] = run; cursor[idx] = run; }
        run += v[i];
    }
}

// bucket exclusive scan (one block, nBk <= 512) -> bcur used as cursors
__global__ __launch_bounds__(512) void bucket_scan_kernel(const int* __restrict__ hb,
                                                          int* __restrict__ bcur, int nBk) {
    __shared__ int sh[512];
    const int tid = threadIdx.x;
    int v = (tid < nBk) ? hb[tid] : 0;
    sh[tid] = v;
    __syncthreads();
    for (int off = 1; off < 512; off <<= 1) {
        int t = (tid >= off) ? sh[tid - off] : 0;
        __syncthreads();
        sh[tid] += t;
        __syncthreads();
    }
    if (tid < nBk) bcur[tid] = sh[tid] - v;   // exclusive
}

// partition edges into bucket-ordered staging (append-sequential writes)
__global__ void partition_kernel(const void* __restrict__ src, const void* __restrict__ dst,
                                 const int* __restrict__ flag, int* __restrict__ bcur,
                                 int2* __restrict__ ebuf, int nE) {
    int t = blockIdx.x * blockDim.x + threadIdx.x;
    if (t >= nE) return;
    int is64 = *flag;
    int d = load_idx(dst, t, is64);
    int s = load_idx(src, t, is64);
    int p = atomicAdd(&bcur[d >> 8], 1);
    ebuf[p] = make_int2(d, s);
}

// fine fill from bucket-ordered edges: col writes stay in ~16 KB windows
__global__ void fill2_kernel(const int2* __restrict__ ebuf, int* __restrict__ cursor,
                             int* __restrict__ col, int nE) {
    int t = blockIdx.x * blockDim.x + threadIdx.x;
    if (t >= nE) return;
    int2 e = ebuf[t];
    int pos = atomicAdd(&cursor[e.x], 1);
    col[pos] = e.y;
}

// ---------------- f32 -> fp16 conversion -------------------------------------
__global__ void tofp16_kernel(const float4* __restrict__ in, uint2* __restrict__ out, int n4) {
    int t = blockIdx.x * blockDim.x + threadIdx.x;
    if (t >= n4) return;
    float4 v = in[t];
    __half2 a = __floats2half2_rn(v.x, v.y);
    __half2 b = __floats2half2_rn(v.z, v.w);
    out[t] = make_uint2(*(unsigned*)&a, *(unsigned*)&b);
}

// ---------------- fused gather (fp16 payload): out = relu?(sbuf + mean) ------
template<int F>
__global__ __launch_bounds__(TB) void gather_fused_h(
        const uint2* __restrict__ xh, const int* __restrict__ col,
        const int* __restrict__ rowptr,
        const float* __restrict__ sbuf, const float* __restrict__ hcopy,
        float* __restrict__ out, int M, int ldout, int doRelu) {
    constexpr int C4 = F / 4;      // 8-byte chunks per row: 16 (F=64) or 8 (F=32)
    constexpr int ES = 64 / C4;    // edge slices per wave
    const int wave = threadIdx.x >> 6;
    const int lane = threadIdx.x & 63;
    const int node = blockIdx.x * (TB / 64) + wave;
    if (node >= M) return;
    const int c4 = lane & (C4 - 1);
    const int es = lane >> (F == 64 ? 4 : 3);

    const int s = rowptr[node], e = rowptr[node + 1];
    float ax = 0.f, ay = 0.f, az = 0.f, aw = 0.f;
    int j = s + es;
    for (; j + ES < e; j += 2 * ES) {
        int cs0 = col[j];
        int cs1 = col[j + ES];
        uint2 u0 = xh[(size_t)cs0 * C4 + c4];
        uint2 u1 = xh[(size_t)cs1 * C4 + c4];
        float2 f0 = __half22float2(*(__half2*)&u0.x);
        float2 f1 = __half22float2(*(__half2*)&u0.y);
        float2 g0 = __half22float2(*(__half2*)&u1.x);
        float2 g1 = __half22float2(*(__half2*)&u1.y);
        ax += f0.x + g0.x; ay += f0.y + g0.y;
        az += f1.x + g1.x; aw += f1.y + g1.y;
    }
    if (j < e) {
        int cs = col[j];
        uint2 u = xh[(size_t)cs * C4 + c4];
        float2 f0 = __half22float2(*(__half2*)&u.x);
        float2 f1 = __half22float2(*(__half2*)&u.y);
        ax += f0.x; ay += f0.y; az += f1.x; aw += f1.y;
    }
    #pragma unroll
    for (int d = C4; d < 64; d <<= 1) {
        ax += __shfl_xor(ax, d);
        ay += __shfl_xor(ay, d);
        az += __shfl_xor(az, d);
        aw += __shfl_xor(aw, d);
    }
    if (es == 0) {
        const float inv = 1.0f / fmaxf((float)(e - s), 1.0f);
        float4 v = make_float4(ax * inv, ay * inv, az * inv, aw * inv);
        if (sbuf) {
            float4 sv = *(const float4*)(sbuf + (size_t)node * F + 4 * c4);
            v.x += sv.x; v.y += sv.y; v.z += sv.z; v.w += sv.w;
        }
        if (doRelu) {
            v.x = fmaxf(v.x, 0.f); v.y = fmaxf(v.y, 0.f);
            v.z = fmaxf(v.z, 0.f); v.w = fmaxf(v.w, 0.f);
        }
        float* orow = out + (size_t)node * ldout;
        *(float4*)(orow + 4 * c4) = v;
        if (hcopy) {
            float4 hv = *(const float4*)(hcopy + (size_t)node * F + 4 * c4);
            *(float4*)(orow + F + 4 * c4) = hv;
        }
    }
}

// ---------------- LDS-staged dual-OUTPUT GEMM: Yh = fp16(A@Wn); S = A@Ws + b -
template<int K, int N>
__global__ __launch_bounds__(TB) void gemm_dualout_lds(
        const float* __restrict__ A, const float* __restrict__ Wn,
        const float* __restrict__ Ws, const float* __restrict__ bias,
        __half* __restrict__ Yh, float* __restrict__ S, int M) {
    constexpr int C = N / 8;
    constexpr int NC4 = C / 4;
    constexpr int KC0 = 2048 / N;
    constexpr int KC = KC0 < K ? KC0 : K;
    constexpr int P4 = (KC * N) / 1024;

    __shared__ float lwn[KC * N];
    __shared__ float lws[KC * N];

    const int tid = threadIdx.x;
    const int colg = tid & 7;
    const int rowg = tid >> 3;
    const int row0 = blockIdx.x * 64 + rowg * 2;
    const bool valid = row0 < M;
    const int c0 = colg * C;

    float4 accY[2][NC4], accS[2][NC4];
    #pragma unroll
    for (int r = 0; r < 2; ++r)
        #pragma unroll
        for (int j = 0; j < NC4; ++j) {
            accY[r][j] = make_float4(0.f, 0.f, 0.f, 0.f);
            accS[r][j] = make_float4(0.f, 0.f, 0.f, 0.f);
        }

    for (int kc = 0; kc < K; kc += KC) {
        __syncthreads();
        const float4* gwn = (const float4*)(Wn + (size_t)kc * N);
        const float4* gws = (const float4*)(Ws + (size_t)kc * N);
        #pragma unroll
        for (int i = 0; i < P4; ++i) {
            int f4i = tid + i * 256;
            ((float4*)lwn)[f4i] = gwn[f4i];
            ((float4*)lws)[f4i] = gws[f4i];
        }
        __syncthreads();
        if (valid) {
            const float* a = A + (size_t)row0 * K + kc;
            for (int k = 0; k < KC; k += 4) {
                float4 av[2];
                #pragma unroll
                for (int r = 0; r < 2; ++r)
                    av[r] = *(const float4*)(a + (size_t)r * K + k);
                #pragma unroll
                for (int kk = 0; kk < 4; ++kk) {
                    #pragma unroll
                    for (int j = 0; j < NC4; ++j) {
                        float4 wn = *(const float4*)(&lwn[(k + kk) * N + c0 + 4 * j]);
                        float4 ws = *(const float4*)(&lws[(k + kk) * N + c0 + 4 * j]);
                        #pragma unroll
                        for (int r = 0; r < 2; ++r) {
                            float ar = ((const float*)&av[r])[kk];
                            accY[r][j].x += ar * wn.x; accY[r][j].y += ar * wn.y;
                            accY[r][j].z += ar * wn.z; accY[r][j].w += ar * wn.w;
                            accS[r][j].x += ar * ws.x; accS[r][j].y += ar * ws.y;
                            accS[r][j].z += ar * ws.z; accS[r][j].w += ar * ws.w;
                        }
                    }
                }
            }
        }
    }

    if (valid) {
        #pragma unroll
        for (int j = 0; j < NC4; ++j) {
            const int c = c0 + 4 * j;
            float4 bb = *(const float4*)(bias + c);
            #pragma unroll
            for (int r = 0; r < 2; ++r) {
                const int row = row0 + r;
                float4 y = accY[r][j];
                __half2 p0 = __floats2half2_rn(y.x, y.y);
                __half2 p1 = __floats2half2_rn(y.z, y.w);
                *(uint2*)(Yh + (size_t)row * N + c) =
                    make_uint2(*(unsigned*)&p0, *(unsigned*)&p1);
                float4 v = accS[r][j];
                v.x += bb.x; v.y += bb.y; v.z += bb.z; v.w += bb.w;
                *(float4*)(S + (size_t)row * N + c) = v;
            }
        }
    }
}

// ---------------- LDS-staged dual-INPUT GEMM: out = relu(A@W + A2@W2 + b) ----
template<int K, int N>
__global__ __launch_bounds__(TB) void gemm_dualin_lds(
        const float* __restrict__ A, const float* __restrict__ W,
        const float* __restrict__ A2, const float* __restrict__ W2,
        const float* __restrict__ bias, float* __restrict__ out, int M) {
    constexpr int C = N / 8;
    constexpr int NC4 = C / 4;
    constexpr int KC0 = 2048 / N;
    constexpr int KC = KC0 < K ? KC0 : K;
    constexpr int P4 = (KC * N) / 1024;

    __shared__ float lw[KC * N];
    __shared__ float lw2[KC * N];

    const int tid = threadIdx.x;
    const int colg = tid & 7;
    const int rowg = tid >> 3;
    const int row0 = blockIdx.x * 64 + rowg * 2;
    const bool valid = row0 < M;
    const int c0 = colg * C;

    float4 acc[2][NC4];
    #pragma unroll
    for (int r = 0; r < 2; ++r)
        #pragma unroll
        for (int j = 0; j < NC4; ++j) acc[r][j] = make_float4(0.f, 0.f, 0.f, 0.f);

    for (int kc = 0; kc < K; kc += KC) {
        __syncthreads();
        const float4* gw  = (const float4*)(W  + (size_t)kc * N);
        const float4* gw2 = (const float4*)(W2 + (size_t)kc * N);
        #pragma unroll
        for (int i = 0; i < P4; ++i) {
            int f4i = tid + i * 256;
            ((float4*)lw)[f4i]  = gw[f4i];
            ((float4*)lw2)[f4i] = gw2[f4i];
        }
        __syncthreads();
        if (valid) {
            const float* a  = A  + (size_t)row0 * K + kc;
            const float* a2 = A2 + (size_t)row0 * K + kc;
            for (int k = 0; k < KC; k += 4) {
                float4 av[2], av2[2];
                #pragma unroll
                for (int r = 0; r < 2; ++r) {
                    av[r]  = *(const float4*)(a  + (size_t)r * K + k);
                    av2[r] = *(const float4*)(a2 + (size_t)r * K + k);
                }
                #pragma unroll
                for (int kk = 0; kk < 4; ++kk) {
                    #pragma unroll
                    for (int j = 0; j < NC4; ++j) {
                        float4 wv  = *(const float4*)(&lw[(k + kk) * N + c0 + 4 * j]);
                        float4 wv2 = *(const float4*)(&lw2[(k + kk) * N + c0 + 4 * j]);
                        #pragma unroll
                        for (int r = 0; r < 2; ++r) {
                            float ar  = ((const float*)&av[r])[kk];
                            float ar2 = ((const float*)&av2[r])[kk];
                            acc[r][j].x += ar * wv.x + ar2 * wv2.x;
                            acc[r][j].y += ar * wv.y + ar2 * wv2.y;
                            acc[r][j].z += ar * wv.z + ar2 * wv2.z;
                            acc[r][j].w += ar * wv.w + ar2 * wv2.w;
                        }
                    }
                }
            }
        }
    }

    if (valid) {
        #pragma unroll
        for (int j = 0; j < NC4; ++j) {
            const int c = c0 + 4 * j;
            float4 bb = *(const float4*)(bias + c);
            #pragma unroll
            for (int r = 0; r < 2; ++r) {
                float4 v = acc[r][j];
                v.x = fmaxf(v.x + bb.x, 0.f);
                v.y = fmaxf(v.y + bb.y, 0.f);
                v.z = fmaxf(v.z + bb.z, 0.f);
                v.w = fmaxf(v.w + bb.w, 0.f);
                *(float4*)(out + (size_t)(row0 + r) * N + c) = v;
            }
        }
    }
}

// ---------------- host orchestration ----------------------------------------
static inline int cdiv_i(long long a, int b) { return (int)((a + b - 1) / b); }

template<int F>
static void launch_gather(const __half* xh, const int* col, const int* rowptr,
                          const float* sbuf, const float* hcopy,
                          float* out, int M, int ldout, int relu, hipStream_t stream) {
    hipLaunchKernelGGL((gather_fused_h<F>), dim3(cdiv_i(M, TB / 64)), dim3(TB), 0, stream,
                       (const uint2*)xh, col, rowptr, sbuf, hcopy, out, M, ldout, relu);
}

extern "C" void kernel_launch(void* const* d_in, const int* in_sizes, int n_in,
                              void* d_out, int out_size, void* d_ws, size_t ws_size,
                              hipStream_t stream) {
    const float* in_feat = (const float*)d_in[0];
    const void* src = d_in[1];
    const void* dst = d_in[2];
    const float* Ws1 = (const float*)d_in[3];  const float* Wn1 = (const float*)d_in[4];  const float* b1 = (const float*)d_in[5];
    const float* Ws2 = (const float*)d_in[6];  const float* Wn2 = (const float*)d_in[7];  const float* b2 = (const float*)d_in[8];
    const float* Ws3 = (const float*)d_in[9];  const float* Wn3 = (const float*)d_in[10]; const float* b3 = (const float*)d_in[11];
    const float* Ws4 = (const float*)d_in[12]; const float* Wn4 = (const float*)d_in[13]; const float* b4 = (const float*)d_in[14];
    const float* Ws5 = (const float*)d_in[15]; const float* Wn5 = (const float*)d_in[16]; const float* b5 = (const float*)d_in[17];
    const float* Ws6 = (const float*)d_in[18]; const float* Wn6 = (const float*)d_in[19]; const float* b6 = (const float*)d_in[20];

    const int M  = in_sizes[0] / 64;   // 100000 nodes
    const int nE = in_sizes[1];        // 1600000 edges
    const int nB  = cdiv_i(M, CHUNK);  // scan chunks (49)
    const int nBk = cdiv_i(M, 256);    // coarse buckets (391)

    // workspace layout
    float* ws    = (float*)d_ws;
    float* P1    = ws;                       // M*128
    float* P2    = P1 + (size_t)M * 128;     // M*64
    float* P3    = P2 + (size_t)M * 64;      // M*32
    float* sbuf  = P3 + (size_t)M * 32;      // M*64
    float* ybuf  = sbuf + (size_t)M * 64;    // M*64 (layer-1 f32 agg; aliased ebuf during build)
    __half* yh   = (__half*)(ybuf + (size_t)M * 64);  // M*64 halves (aliased xh pre-layer-2)
    int* deg     = (int*)((float*)yh + (size_t)M * 32);
    int* hb      = deg + M;                  // NBK
    int* cursor  = hb + NBK;                 // M
    int* rowptr  = cursor + M;               // M+1
    int* col     = rowptr + (M + 1);         // nE
    int* bsum    = col + nE;                 // 64
    int* boff    = bsum + 64;                // 64
    int* bcur    = boff + 64;                // NBK
    int* flag    = bcur + NBK;               // 1
    int2* ebuf   = (int2*)ybuf;              // nE int2 (during CSR build only)
    __half* xh   = yh;                       // fp16 in_feat (until layer-2 GEMM)

    // ---- CSR build
    hipLaunchKernelGGL(detect_idx_kernel, dim3(1), dim3(TB), 0, stream,
                       (const int*)src, (const int*)dst, nE, flag);
    hipMemsetAsync(deg, 0, (size_t)(M + NBK) * sizeof(int), stream);  // deg + hb
    hipLaunchKernelGGL(hist2_kernel, dim3(cdiv_i(nE, TB)), dim3(TB), 0, stream,
                       dst, flag, deg, hb, nE);
    hipLaunchKernelGGL(bsum_kernel, dim3(nB), dim3(TB), 0, stream, deg, bsum, M);
    hipLaunchKernelGGL(topscan_kernel, dim3(1), dim3(64), 0, stream,
                       bsum, boff, rowptr, nB, M);
    hipLaunchKernelGGL(scan_chunk_kernel, dim3(nB), dim3(TB), 0, stream,
                       deg, boff, rowptr, cursor, M);
    hipLaunchKernelGGL(bucket_scan_kernel, dim3(1), dim3(512), 0, stream, hb, bcur, nBk);
    hipLaunchKernelGGL(partition_kernel, dim3(cdiv_i(nE, TB)), dim3(TB), 0, stream,
                       src, dst, flag, bcur, ebuf, nE);
    hipLaunchKernelGGL(fill2_kernel, dim3(cdiv_i(nE, TB)), dim3(TB), 0, stream,
                       ebuf, cursor, col, nE);

    // fp16 copy of in_feat for the layer-1 gather
    hipLaunchKernelGGL(tofp16_kernel, dim3(cdiv_i((long long)M * 16, TB)), dim3(TB), 0, stream,
                       (const float4*)in_feat, (uint2*)xh, M * 16);

    const int gblocks = cdiv_i(M, 64);

    // ---- layer 1: 64 -> 128, relu.  ybuf = mean_nbr(in_feat); dual-input GEMM
    launch_gather<64>(xh, col, rowptr, nullptr, nullptr, ybuf, M, 64, 0, stream);
    hipLaunchKernelGGL((gemm_dualin_lds<64, 128>), dim3(gblocks), dim3(TB), 0, stream,
                       in_feat, Ws1, ybuf, Wn1, b1, P1, M);

    // ---- layer 2: 128 -> 64, relu
    hipLaunchKernelGGL((gemm_dualout_lds<128, 64>), dim3(gblocks), dim3(TB), 0, stream,
                       P1, Wn2, Ws2, b2, yh, sbuf, M);
    launch_gather<64>(yh, col, rowptr, sbuf, nullptr, P2, M, 64, 1, stream);

    // ---- layer 3: 64 -> 32, relu
    hipLaunchKernelGGL((gemm_dualout_lds<64, 32>), dim3(gblocks), dim3(TB), 0, stream,
                       P2, Wn3, Ws3, b3, yh, sbuf, M);
    launch_gather<32>(yh, col, rowptr, sbuf, nullptr, P3, M, 32, 1, stream);

    // ---- layer 4: 32 -> 32, relu, concat h3 -> h4 (64 wide) in P2
    hipLaunchKernelGGL((gemm_dualout_lds<32, 32>), dim3(gblocks), dim3(TB), 0, stream,
                       P3, Wn4, Ws4, b4, yh, sbuf, M);
    launch_gather<32>(yh, col, rowptr, sbuf, P3, P2, M, 64, 1, stream);

    // ---- layer 5: 64 -> 64, relu, concat h4 -> h5 (128 wide) in P1
    hipLaunchKernelGGL((gemm_dualout_lds<64, 64>), dim3(gblocks), dim3(TB), 0, stream,
                       P2, Wn5, Ws5, b5, yh, sbuf, M);
    launch_gather<64>(yh, col, rowptr, sbuf, P2, P1, M, 128, 1, stream);

    // ---- layer 6: 128 -> 64, no relu, to d_out
    hipLaunchKernelGGL((gemm_dualout_lds<128, 64>), dim3(gblocks), dim3(TB), 0, stream,
                       P1, Wn6, Ws6, b6, yh, sbuf, M);
    launch_gather<64>(yh, col, rowptr, sbuf, nullptr, (float*)d_out, M, 64, 0, stream);
}

// Round 8
// 702.128 us; speedup vs baseline: 2.4757x; 2.4757x over previous
//
#include <hip/hip_runtime.h>
#include <hip/hip_fp16.h>

#define TB 256
#define CHUNK 2048
#define NBK 512     // bucket array capacity (actual buckets = cdiv(M,256) <= 512)
#define NBLK_P 128  // partition blocks (H-matrix rows)

// ---------------- index-width detection (int32 vs int64 src/dst) -------------
__global__ void detect_idx_kernel(const int* __restrict__ s32, const int* __restrict__ d32,
                                  int nE, int* __restrict__ flag) {
    __shared__ int nz;
    if (threadIdx.x == 0) nz = 0;
    __syncthreads();
    int n = nE < 2048 ? nE : 2048;
    int local = 0;
    for (int i = threadIdx.x; i < n; i += blockDim.x) {
        if (s32[2 * i + 1] != 0 || d32[2 * i + 1] != 0) local = 1;
    }
    if (local) atomicOr(&nz, 1);
    __syncthreads();
    if (threadIdx.x == 0) *flag = (nz == 0) ? 1 : 0;   // 1 => indices are int64
}

__device__ __forceinline__ int load_idx(const void* p, int e, int is64) {
    return is64 ? (int)((const long long*)p)[e] : ((const int*)p)[e];
}

// ---------------- CSR build --------------------------------------------------
// per-dst degree histogram (100K counters -> low contention; round-6 proven)
__global__ void hist_kernel(const void* __restrict__ dst, const int* __restrict__ flag,
                            int* __restrict__ deg, int nE) {
    int t = blockIdx.x * blockDim.x + threadIdx.x;
    if (t >= nE) return;
    atomicAdd(&deg[load_idx(dst, t, *flag)], 1);
}

// stage A: per-chunk sums (CHUNK=2048 elems per 256-thread block, 8/thread)
__global__ __launch_bounds__(TB) void bsum_kernel(const int* __restrict__ deg,
                                                  int* __restrict__ bsum, int M) {
    const int tid = threadIdx.x;
    const int base = blockIdx.x * CHUNK + tid * 8;
    int s = 0;
    if (base + 8 <= M) {
        int4 a = *(const int4*)(deg + base);
        int4 c = *(const int4*)(deg + base + 4);
        s = a.x + a.y + a.z + a.w + c.x + c.y + c.z + c.w;
    } else {
        for (int i = 0; i < 8; ++i) if (base + i < M) s += deg[base + i];
    }
    #pragma unroll
    for (int off = 1; off < 64; off <<= 1) s += __shfl_xor(s, off);
    __shared__ int wsum[4];
    const int lane = tid & 63, wv = tid >> 6;
    if (lane == 0) wsum[wv] = s;
    __syncthreads();
    if (tid == 0) bsum[blockIdx.x] = wsum[0] + wsum[1] + wsum[2] + wsum[3];
}

// stage B: one wave exclusive-scans chunk sums (nB <= 64), writes rowptr[M]
__global__ void topscan_kernel(const int* __restrict__ bsum, int* __restrict__ boff,
                               int* __restrict__ rowptr, int nB, int M) {
    const int tid = threadIdx.x;   // 64 threads
    int v = (tid < nB) ? bsum[tid] : 0;
    int x = v;
    #pragma unroll
    for (int off = 1; off < 64; off <<= 1) {
        int y = __shfl_up(x, off);
        if (tid >= off) x += y;
    }
    if (tid < nB) boff[tid] = x - v;
    if (tid == 63) rowptr[M] = x;
}

// stage C: chunk-local exclusive scan + chunk offset -> rowptr and cursor
__global__ __launch_bounds__(TB) void scan_chunk_kernel(
        const int* __restrict__ deg, const int* __restrict__ boff,
        int* __restrict__ rowptr, int* __restrict__ cursor, int M) {
    const int tid = threadIdx.x;
    const int base = blockIdx.x * CHUNK + tid * 8;
    int v[8];
    if (base + 8 <= M) {
        int4 a = *(const int4*)(deg + base);
        int4 c = *(const int4*)(deg + base + 4);
        v[0] = a.x; v[1] = a.y; v[2] = a.z; v[3] = a.w;
        v[4] = c.x; v[5] = c.y; v[6] = c.z; v[7] = c.w;
    } else {
        #pragma unroll
        for (int i = 0; i < 8; ++i) v[i] = (base + i < M) ? deg[base + i] : 0;
    }
    int tsum = 0;
    #pragma unroll
    for (int i = 0; i < 8; ++i) tsum += v[i];
    const int lane = tid & 63, wv = tid >> 6;
    int x = tsum;
    #pragma unroll
    for (int off = 1; off < 64; off <<= 1) {
        int y = __shfl_up(x, off);
        if (lane >= off) x += y;
    }
    __shared__ int wsum[4];
    if (lane == 63) wsum[wv] = x;
    __syncthreads();
    int wbase = 0;
    #pragma unroll
    for (int w = 0; w < 4; ++w) if (w < wv) wbase += wsum[w];
    int run = boff[blockIdx.x] + wbase + (x - tsum);
    #pragma unroll
    for (int i = 0; i < 8; ++i) {
        int idx = base + i;
        if (idx < M) { rowptr[idx] = run; cursor[idx] = run; }
        run += v[i];
    }
}

// partition pass A: per-block LDS histogram of coarse buckets -> H[block][bucket]
__global__ __launch_bounds__(TB) void passA_kernel(
        const void* __restrict__ dst, const int* __restrict__ flag,
        int* __restrict__ H, int nE, int EC, int nBk) {
    __shared__ int lh[NBK];
    for (int i = threadIdx.x; i < NBK; i += TB) lh[i] = 0;
    __syncthreads();
    const int is64 = *flag;
    const int lo = blockIdx.x * EC;
    const int hi = min(nE, lo + EC);
    for (int j = lo + threadIdx.x; j < hi; j += TB) {
        int d = load_idx(dst, j, is64);
        atomicAdd(&lh[d >> 8], 1);
    }
    __syncthreads();
    for (int i = threadIdx.x; i < nBk; i += TB) H[blockIdx.x * nBk + i] = lh[i];
}

// column-wise exclusive scan of H (over blocks), totals -> T
__global__ __launch_bounds__(TB) void colscan_kernel(int* __restrict__ H,
                                                     int* __restrict__ T, int nBk) {
    int t = blockIdx.x * blockDim.x + threadIdx.x;
    if (t >= nBk) return;
    int run = 0;
    for (int b = 0; b < NBLK_P; ++b) {
        int v = H[b * nBk + t];
        H[b * nBk + t] = run;
        run += v;
    }
    T[t] = run;
}

// bucket exclusive scan (one block, nBk <= 512): T -> Bbase
__global__ __launch_bounds__(512) void bucket_scan_kernel(const int* __restrict__ hb,
                                                          int* __restrict__ bcur, int nBk) {
    __shared__ int sh[512];
    const int tid = threadIdx.x;
    int v = (tid < nBk) ? hb[tid] : 0;
    sh[tid] = v;
    __syncthreads();
    for (int off = 1; off < 512; off <<= 1) {
        int t = (tid >= off) ? sh[tid - off] : 0;
        __syncthreads();
        sh[tid] += t;
        __syncthreads();
    }
    if (tid < nBk) bcur[tid] = sh[tid] - v;   // exclusive
}

// partition pass B: scatter edges to bucket-ordered ebuf, zero global atomics
__global__ __launch_bounds__(TB) void passB_kernel(
        const void* __restrict__ src, const void* __restrict__ dst,
        const int* __restrict__ flag, const int* __restrict__ H,
        const int* __restrict__ Bbase, int2* __restrict__ ebuf,
        int nE, int EC, int nBk) {
    __shared__ int lbase[NBK];
    __shared__ int lcur[NBK];
    for (int i = threadIdx.x; i < nBk; i += TB) {
        lbase[i] = Bbase[i] + H[blockIdx.x * nBk + i];
        lcur[i] = 0;
    }
    __syncthreads();
    const int is64 = *flag;
    const int lo = blockIdx.x * EC;
    const int hi = min(nE, lo + EC);
    for (int j = lo + threadIdx.x; j < hi; j += TB) {
        int d = load_idx(dst, j, is64);
        int s = load_idx(src, j, is64);
        int bk = d >> 8;
        int p = lbase[bk] + atomicAdd(&lcur[bk], 1);
        ebuf[p] = make_int2(d, s);
    }
}

// fine fill from bucket-ordered edges: cursor atomics + col writes stay local
__global__ void fill2_kernel(const int2* __restrict__ ebuf, int* __restrict__ cursor,
                             int* __restrict__ col, int nE) {
    int t = blockIdx.x * blockDim.x + threadIdx.x;
    if (t >= nE) return;
    int2 e = ebuf[t];
    int pos = atomicAdd(&cursor[e.x], 1);
    col[pos] = e.y;
}

// ---------------- f32 -> fp16 conversion -------------------------------------
__global__ void tofp16_kernel(const float4* __restrict__ in, uint2* __restrict__ out, int n4) {
    int t = blockIdx.x * blockDim.x + threadIdx.x;
    if (t >= n4) return;
    float4 v = in[t];
    __half2 a = __floats2half2_rn(v.x, v.y);
    __half2 b = __floats2half2_rn(v.z, v.w);
    out[t] = make_uint2(*(unsigned*)&a, *(unsigned*)&b);
}

// ---------------- fused gather (fp16 payload): out = relu?(sbuf + mean) ------
template<int F>
__global__ __launch_bounds__(TB) void gather_fused_h(
        const uint2* __restrict__ xh, const int* __restrict__ col,
        const int* __restrict__ rowptr,
        const float* __restrict__ sbuf, const float* __restrict__ hcopy,
        float* __restrict__ out, int M, int ldout, int doRelu) {
    constexpr int C4 = F / 4;      // 8-byte chunks per row: 16 (F=64) or 8 (F=32)
    constexpr int ES = 64 / C4;    // edge slices per wave
    const int wave = threadIdx.x >> 6;
    const int lane = threadIdx.x & 63;
    const int node = blockIdx.x * (TB / 64) + wave;
    if (node >= M) return;
    const int c4 = lane & (C4 - 1);
    const int es = lane >> (F == 64 ? 4 : 3);

    const int s = rowptr[node], e = rowptr[node + 1];
    float ax = 0.f, ay = 0.f, az = 0.f, aw = 0.f;
    int j = s + es;
    for (; j + ES < e; j += 2 * ES) {
        int cs0 = col[j];
        int cs1 = col[j + ES];
        uint2 u0 = xh[(size_t)cs0 * C4 + c4];
        uint2 u1 = xh[(size_t)cs1 * C4 + c4];
        float2 f0 = __half22float2(*(__half2*)&u0.x);
        float2 f1 = __half22float2(*(__half2*)&u0.y);
        float2 g0 = __half22float2(*(__half2*)&u1.x);
        float2 g1 = __half22float2(*(__half2*)&u1.y);
        ax += f0.x + g0.x; ay += f0.y + g0.y;
        az += f1.x + g1.x; aw += f1.y + g1.y;
    }
    if (j < e) {
        int cs = col[j];
        uint2 u = xh[(size_t)cs * C4 + c4];
        float2 f0 = __half22float2(*(__half2*)&u.x);
        float2 f1 = __half22float2(*(__half2*)&u.y);
        ax += f0.x; ay += f0.y; az += f1.x; aw += f1.y;
    }
    #pragma unroll
    for (int d = C4; d < 64; d <<= 1) {
        ax += __shfl_xor(ax, d);
        ay += __shfl_xor(ay, d);
        az += __shfl_xor(az, d);
        aw += __shfl_xor(aw, d);
    }
    if (es == 0) {
        const float inv = 1.0f / fmaxf((float)(e - s), 1.0f);
        float4 v = make_float4(ax * inv, ay * inv, az * inv, aw * inv);
        if (sbuf) {
            float4 sv = *(const float4*)(sbuf + (size_t)node * F + 4 * c4);
            v.x += sv.x; v.y += sv.y; v.z += sv.z; v.w += sv.w;
        }
        if (doRelu) {
            v.x = fmaxf(v.x, 0.f); v.y = fmaxf(v.y, 0.f);
            v.z = fmaxf(v.z, 0.f); v.w = fmaxf(v.w, 0.f);
        }
        float* orow = out + (size_t)node * ldout;
        *(float4*)(orow + 4 * c4) = v;
        if (hcopy) {
            float4 hv = *(const float4*)(hcopy + (size_t)node * F + 4 * c4);
            *(float4*)(orow + F + 4 * c4) = hv;
        }
    }
}

// ---------------- LDS-staged dual-OUTPUT GEMM: Yh = fp16(A@Wn); S = A@Ws + b -
template<int K, int N>
__global__ __launch_bounds__(TB) void gemm_dualout_lds(
        const float* __restrict__ A, const float* __restrict__ Wn,
        const float* __restrict__ Ws, const float* __restrict__ bias,
        __half* __restrict__ Yh, float* __restrict__ S, int M) {
    constexpr int C = N / 8;
    constexpr int NC4 = C / 4;
    constexpr int KC0 = 2048 / N;
    constexpr int KC = KC0 < K ? KC0 : K;
    constexpr int P4 = (KC * N) / 1024;

    __shared__ float lwn[KC * N];
    __shared__ float lws[KC * N];

    const int tid = threadIdx.x;
    const int colg = tid & 7;
    const int rowg = tid >> 3;
    const int row0 = blockIdx.x * 64 + rowg * 2;
    const bool valid = row0 < M;
    const int c0 = colg * C;

    float4 accY[2][NC4], accS[2][NC4];
    #pragma unroll
    for (int r = 0; r < 2; ++r)
        #pragma unroll
        for (int j = 0; j < NC4; ++j) {
            accY[r][j] = make_float4(0.f, 0.f, 0.f, 0.f);
            accS[r][j] = make_float4(0.f, 0.f, 0.f, 0.f);
        }

    for (int kc = 0; kc < K; kc += KC) {
        __syncthreads();
        const float4* gwn = (const float4*)(Wn + (size_t)kc * N);
        const float4* gws = (const float4*)(Ws + (size_t)kc * N);
        #pragma unroll
        for (int i = 0; i < P4; ++i) {
            int f4i = tid + i * 256;
            ((float4*)lwn)[f4i] = gwn[f4i];
            ((float4*)lws)[f4i] = gws[f4i];
        }
        __syncthreads();
        if (valid) {
            const float* a = A + (size_t)row0 * K + kc;
            for (int k = 0; k < KC; k += 4) {
                float4 av[2];
                #pragma unroll
                for (int r = 0; r < 2; ++r)
                    av[r] = *(const float4*)(a + (size_t)r * K + k);
                #pragma unroll
                for (int kk = 0; kk < 4; ++kk) {
                    #pragma unroll
                    for (int j = 0; j < NC4; ++j) {
                        float4 wn = *(const float4*)(&lwn[(k + kk) * N + c0 + 4 * j]);
                        float4 ws = *(const float4*)(&lws[(k + kk) * N + c0 + 4 * j]);
                        #pragma unroll
                        for (int r = 0; r < 2; ++r) {
                            float ar = ((const float*)&av[r])[kk];
                            accY[r][j].x += ar * wn.x; accY[r][j].y += ar * wn.y;
                            accY[r][j].z += ar * wn.z; accY[r][j].w += ar * wn.w;
                            accS[r][j].x += ar * ws.x; accS[r][j].y += ar * ws.y;
                            accS[r][j].z += ar * ws.z; accS[r][j].w += ar * ws.w;
                        }
                    }
                }
            }
        }
    }

    if (valid) {
        #pragma unroll
        for (int j = 0; j < NC4; ++j) {
            const int c = c0 + 4 * j;
            float4 bb = *(const float4*)(bias + c);
            #pragma unroll
            for (int r = 0; r < 2; ++r) {
                const int row = row0 + r;
                float4 y = accY[r][j];
                __half2 p0 = __floats2half2_rn(y.x, y.y);
                __half2 p1 = __floats2half2_rn(y.z, y.w);
                *(uint2*)(Yh + (size_t)row * N + c) =
                    make_uint2(*(unsigned*)&p0, *(unsigned*)&p1);
                float4 v = accS[r][j];
                v.x += bb.x; v.y += bb.y; v.z += bb.z; v.w += bb.w;
                *(float4*)(S + (size_t)row * N + c) = v;
            }
        }
    }
}

// ---------------- LDS-staged dual-INPUT GEMM: out = relu(A@W + A2@W2 + b) ----
template<int K, int N>
__global__ __launch_bounds__(TB) void gemm_dualin_lds(
        const float* __restrict__ A, const float* __restrict__ W,
        const float* __restrict__ A2, const float* __restrict__ W2,
        const float* __restrict__ bias, float* __restrict__ out, int M) {
    constexpr int C = N / 8;
    constexpr int NC4 = C / 4;
    constexpr int KC0 = 2048 / N;
    constexpr int KC = KC0 < K ? KC0 : K;
    constexpr int P4 = (KC * N) / 1024;

    __shared__ float lw[KC * N];
    __shared__ float lw2[KC * N];

    const int tid = threadIdx.x;
    const int colg = tid & 7;
    const int rowg = tid >> 3;
    const int row0 = blockIdx.x * 64 + rowg * 2;
    const bool valid = row0 < M;
    const int c0 = colg * C;

    float4 acc[2][NC4];
    #pragma unroll
    for (int r = 0; r < 2; ++r)
        #pragma unroll
        for (int j = 0; j < NC4; ++j) acc[r][j] = make_float4(0.f, 0.f, 0.f, 0.f);

    for (int kc = 0; kc < K; kc += KC) {
        __syncthreads();
        const float4* gw  = (const float4*)(W  + (size_t)kc * N);
        const float4* gw2 = (const float4*)(W2 + (size_t)kc * N);
        #pragma unroll
        for (int i = 0; i < P4; ++i) {
            int f4i = tid + i * 256;
            ((float4*)lw)[f4i]  = gw[f4i];
            ((float4*)lw2)[f4i] = gw2[f4i];
        }
        __syncthreads();
        if (valid) {
            const float* a  = A  + (size_t)row0 * K + kc;
            const float* a2 = A2 + (size_t)row0 * K + kc;
            for (int k = 0; k < KC; k += 4) {
                float4 av[2], av2[2];
                #pragma unroll
                for (int r = 0; r < 2; ++r) {
                    av[r]  = *(const float4*)(a  + (size_t)r * K + k);
                    av2[r] = *(const float4*)(a2 + (size_t)r * K + k);
                }
                #pragma unroll
                for (int kk = 0; kk < 4; ++kk) {
                    #pragma unroll
                    for (int j = 0; j < NC4; ++j) {
                        float4 wv  = *(const float4*)(&lw[(k + kk) * N + c0 + 4 * j]);
                        float4 wv2 = *(const float4*)(&lw2[(k + kk) * N + c0 + 4 * j]);
                        #pragma unroll
                        for (int r = 0; r < 2; ++r) {
                            float ar  = ((const float*)&av[r])[kk];
                            float ar2 = ((const float*)&av2[r])[kk];
                            acc[r][j].x += ar * wv.x + ar2 * wv2.x;
                            acc[r][j].y += ar * wv.y + ar2 * wv2.y;
                            acc[r][j].z += ar * wv.z + ar2 * wv2.z;
                            acc[r][j].w += ar * wv.w + ar2 * wv2.w;
                        }
                    }
                }
            }
        }
    }

    if (valid) {
        #pragma unroll
        for (int j = 0; j < NC4; ++j) {
            const int c = c0 + 4 * j;
            float4 bb = *(const float4*)(bias + c);
            #pragma unroll
            for (int r = 0; r < 2; ++r) {
                float4 v = acc[r][j];
                v.x = fmaxf(v.x + bb.x, 0.f);
                v.y = fmaxf(v.y + bb.y, 0.f);
                v.z = fmaxf(v.z + bb.z, 0.f);
                v.w = fmaxf(v.w + bb.w, 0.f);
                *(float4*)(out + (size_t)(row0 + r) * N + c) = v;
            }
        }
    }
}

// ---------------- host orchestration ----------------------------------------
static inline int cdiv_i(long long a, int b) { return (int)((a + b - 1) / b); }

template<int F>
static void launch_gather(const __half* xh, const int* col, const int* rowptr,
                          const float* sbuf, const float* hcopy,
                          float* out, int M, int ldout, int relu, hipStream_t stream) {
    hipLaunchKernelGGL((gather_fused_h<F>), dim3(cdiv_i(M, TB / 64)), dim3(TB), 0, stream,
                       (const uint2*)xh, col, rowptr, sbuf, hcopy, out, M, ldout, relu);
}

extern "C" void kernel_launch(void* const* d_in, const int* in_sizes, int n_in,
                              void* d_out, int out_size, void* d_ws, size_t ws_size,
                              hipStream_t stream) {
    const float* in_feat = (const float*)d_in[0];
    const void* src = d_in[1];
    const void* dst = d_in[2];
    const float* Ws1 = (const float*)d_in[3];  const float* Wn1 = (const float*)d_in[4];  const float* b1 = (const float*)d_in[5];
    const float* Ws2 = (const float*)d_in[6];  const float* Wn2 = (const float*)d_in[7];  const float* b2 = (const float*)d_in[8];
    const float* Ws3 = (const float*)d_in[9];  const float* Wn3 = (const float*)d_in[10]; const float* b3 = (const float*)d_in[11];
    const float* Ws4 = (const float*)d_in[12]; const float* Wn4 = (const float*)d_in[13]; const float* b4 = (const float*)d_in[14];
    const float* Ws5 = (const float*)d_in[15]; const float* Wn5 = (const float*)d_in[16]; const float* b5 = (const float*)d_in[17];
    const float* Ws6 = (const float*)d_in[18]; const float* Wn6 = (const float*)d_in[19]; const float* b6 = (const float*)d_in[20];

    const int M  = in_sizes[0] / 64;   // 100000 nodes
    const int nE = in_sizes[1];        // 1600000 edges
    const int nB  = cdiv_i(M, CHUNK);  // scan chunks (49)
    const int nBk = cdiv_i(M, 256);    // coarse buckets (391)
    const int EC  = cdiv_i(nE, NBLK_P);

    // workspace layout
    float* ws    = (float*)d_ws;
    float* P1    = ws;                       // M*128
    float* P2    = P1 + (size_t)M * 128;     // M*64
    float* P3    = P2 + (size_t)M * 64;      // M*32
    float* sbuf  = P3 + (size_t)M * 32;      // M*64
    float* ybuf  = sbuf + (size_t)M * 64;    // M*64 (layer-1 f32 agg; aliased ebuf in build)
    __half* yh   = (__half*)(ybuf + (size_t)M * 64);  // M*64 halves
    int* deg     = (int*)((float*)yh + (size_t)M * 32);  // M
    int* cursor  = deg + M;                  // M
    int* rowptr  = cursor + M;               // M+1
    int* col     = rowptr + (M + 1);         // nE
    int* bsum    = col + nE;                 // 64
    int* boff    = bsum + 64;                // 64
    int* T       = boff + 64;                // NBK
    int* Bbase   = T + NBK;                  // NBK
    int* flag    = Bbase + NBK;              // 1
    int* H       = flag + 1;                 // NBLK_P * NBK
    int2* ebuf   = (int2*)ybuf;              // nE int2 (build only)
    __half* xh   = yh;                       // fp16 in_feat (until layer-2 GEMM)

    // ---- CSR build (contention-free counting sort)
    hipLaunchKernelGGL(detect_idx_kernel, dim3(1), dim3(TB), 0, stream,
                       (const int*)src, (const int*)dst, nE, flag);
    hipMemsetAsync(deg, 0, (size_t)M * sizeof(int), stream);
    hipLaunchKernelGGL(hist_kernel, dim3(cdiv_i(nE, TB)), dim3(TB), 0, stream,
                       dst, flag, deg, nE);
    hipLaunchKernelGGL(bsum_kernel, dim3(nB), dim3(TB), 0, stream, deg, bsum, M);
    hipLaunchKernelGGL(topscan_kernel, dim3(1), dim3(64), 0, stream,
                       bsum, boff, rowptr, nB, M);
    hipLaunchKernelGGL(scan_chunk_kernel, dim3(nB), dim3(TB), 0, stream,
                       deg, boff, rowptr, cursor, M);
    hipLaunchKernelGGL(passA_kernel, dim3(NBLK_P), dim3(TB), 0, stream,
                       dst, flag, H, nE, EC, nBk);
    hipLaunchKernelGGL(colscan_kernel, dim3(cdiv_i(nBk, TB)), dim3(TB), 0, stream,
                       H, T, nBk);
    hipLaunchKernelGGL(bucket_scan_kernel, dim3(1), dim3(512), 0, stream, T, Bbase, nBk);
    hipLaunchKernelGGL(passB_kernel, dim3(NBLK_P), dim3(TB), 0, stream,
                       src, dst, flag, H, Bbase, ebuf, nE, EC, nBk);
    hipLaunchKernelGGL(fill2_kernel, dim3(cdiv_i(nE, TB)), dim3(TB), 0, stream,
                       ebuf, cursor, col, nE);

    // fp16 copy of in_feat for the layer-1 gather
    hipLaunchKernelGGL(tofp16_kernel, dim3(cdiv_i((long long)M * 16, TB)), dim3(TB), 0, stream,
                       (const float4*)in_feat, (uint2*)xh, M * 16);

    const int gblocks = cdiv_i(M, 64);

    // ---- layer 1: 64 -> 128, relu.  ybuf = mean_nbr(in_feat); dual-input GEMM
    launch_gather<64>(xh, col, rowptr, nullptr, nullptr, ybuf, M, 64, 0, stream);
    hipLaunchKernelGGL((gemm_dualin_lds<64, 128>), dim3(gblocks), dim3(TB), 0, stream,
                       in_feat, Ws1, ybuf, Wn1, b1, P1, M);

    // ---- layer 2: 128 -> 64, relu
    hipLaunchKernelGGL((gemm_dualout_lds<128, 64>), dim3(gblocks), dim3(TB), 0, stream,
                       P1, Wn2, Ws2, b2, yh, sbuf, M);
    launch_gather<64>(yh, col, rowptr, sbuf, nullptr, P2, M, 64, 1, stream);

    // ---- layer 3: 64 -> 32, relu
    hipLaunchKernelGGL((gemm_dualout_lds<64, 32>), dim3(gblocks), dim3(TB), 0, stream,
                       P2, Wn3, Ws3, b3, yh, sbuf, M);
    launch_gather<32>(yh, col, rowptr, sbuf, nullptr, P3, M, 32, 1, stream);

    // ---- layer 4: 32 -> 32, relu, concat h3 -> h4 (64 wide) in P2
    hipLaunchKernelGGL((gemm_dualout_lds<32, 32>), dim3(gblocks), dim3(TB), 0, stream,
                       P3, Wn4, Ws4, b4, yh, sbuf, M);
    launch_gather<32>(yh, col, rowptr, sbuf, P3, P2, M, 64, 1, stream);

    // ---- layer 5: 64 -> 64, relu, concat h4 -> h5 (128 wide) in P1
    hipLaunchKernelGGL((gemm_dualout_lds<64, 64>), dim3(gblocks), dim3(TB), 0, stream,
                       P2, Wn5, Ws5, b5, yh, sbuf, M);
    launch_gather<64>(yh, col, rowptr, sbuf, P2, P1, M, 128, 1, stream);

    // ---- layer 6: 128 -> 64, no relu, to d_out
    hipLaunchKernelGGL((gemm_dualout_lds<128, 64>), dim3(gblocks), dim3(TB), 0, stream,
                       P1, Wn6, Ws6, b6, yh, sbuf, M);
    launch_gather<64>(yh, col, rowptr, sbuf, nullptr, (float*)d_out, M, 64, 0, stream);
}

// Round 9
// 604.941 us; speedup vs baseline: 2.8735x; 1.1607x over previous
//
#include <hip/hip_runtime.h>
#include <hip/hip_fp16.h>

#define TB 256
#define NBK 512     // bucket array capacity (actual buckets = cdiv(M,256) <= 512)
#define NBLK_P 128  // partition blocks (H-matrix rows)

// ---------------- index-width detection (int32 vs int64 src/dst) -------------
__global__ void detect_idx_kernel(const int* __restrict__ s32, const int* __restrict__ d32,
                                  int nE, int* __restrict__ flag) {
    __shared__ int nz;
    if (threadIdx.x == 0) nz = 0;
    __syncthreads();
    int n = nE < 2048 ? nE : 2048;
    int local = 0;
    for (int i = threadIdx.x; i < n; i += blockDim.x) {
        if (s32[2 * i + 1] != 0 || d32[2 * i + 1] != 0) local = 1;
    }
    if (local) atomicOr(&nz, 1);
    __syncthreads();
    if (threadIdx.x == 0) *flag = (nz == 0) ? 1 : 0;   // 1 => indices are int64
}

__device__ __forceinline__ int load_idx(const void* p, int e, int is64) {
    return is64 ? (int)((const long long*)p)[e] : ((const int*)p)[e];
}

// ---------------- CSR build: contention-free counting sort -------------------
// pass A: per-block LDS histogram of coarse buckets -> H[block][bucket]
__global__ __launch_bounds__(TB) void passA_kernel(
        const void* __restrict__ dst, const int* __restrict__ flag,
        int* __restrict__ H, int nE, int EC, int nBk) {
    __shared__ int lh[NBK];
    for (int i = threadIdx.x; i < NBK; i += TB) lh[i] = 0;
    __syncthreads();
    const int is64 = *flag;
    const int lo = blockIdx.x * EC;
    const int hi = min(nE, lo + EC);
    for (int j = lo + threadIdx.x; j < hi; j += TB) {
        int d = load_idx(dst, j, is64);
        atomicAdd(&lh[d >> 8], 1);
    }
    __syncthreads();
    for (int i = threadIdx.x; i < nBk; i += TB) H[blockIdx.x * nBk + i] = lh[i];
}

// column-wise exclusive scan of H (over blocks), totals -> T
__global__ __launch_bounds__(TB) void colscan_kernel(int* __restrict__ H,
                                                     int* __restrict__ T, int nBk) {
    int t = blockIdx.x * blockDim.x + threadIdx.x;
    if (t >= nBk) return;
    int run = 0;
    for (int b = 0; b < NBLK_P; ++b) {
        int v = H[b * nBk + t];
        H[b * nBk + t] = run;
        run += v;
    }
    T[t] = run;
}

// bucket exclusive scan (one block, nBk <= 512): T -> Bbase
__global__ __launch_bounds__(512) void bucket_scan_kernel(const int* __restrict__ hb,
                                                          int* __restrict__ bcur, int nBk) {
    __shared__ int sh[512];
    const int tid = threadIdx.x;
    int v = (tid < nBk) ? hb[tid] : 0;
    sh[tid] = v;
    __syncthreads();
    for (int off = 1; off < 512; off <<= 1) {
        int t = (tid >= off) ? sh[tid - off] : 0;
        __syncthreads();
        sh[tid] += t;
        __syncthreads();
    }
    if (tid < nBk) bcur[tid] = sh[tid] - v;   // exclusive
}

// pass B: scatter edges to bucket-ordered ebuf, zero global atomics
__global__ __launch_bounds__(TB) void passB_kernel(
        const void* __restrict__ src, const void* __restrict__ dst,
        const int* __restrict__ flag, const int* __restrict__ H,
        const int* __restrict__ Bbase, int2* __restrict__ ebuf,
        int nE, int EC, int nBk) {
    __shared__ int lbase[NBK];
    __shared__ int lcur[NBK];
    for (int i = threadIdx.x; i < nBk; i += TB) {
        lbase[i] = Bbase[i] + H[blockIdx.x * nBk + i];
        lcur[i] = 0;
    }
    __syncthreads();
    const int is64 = *flag;
    const int lo = blockIdx.x * EC;
    const int hi = min(nE, lo + EC);
    for (int j = lo + threadIdx.x; j < hi; j += TB) {
        int d = load_idx(dst, j, is64);
        int s = load_idx(src, j, is64);
        int bk = d >> 8;
        int p = lbase[bk] + atomicAdd(&lcur[bk], 1);
        ebuf[p] = make_int2(d, s);
    }
}

// bucket build: one block per bucket (256 contiguous node ids, contiguous edges).
// LDS degree count -> LDS scan -> rowptr; LDS cursors -> col fill.
__global__ __launch_bounds__(TB) void bucket_build_kernel(
        const int2* __restrict__ ebuf, const int* __restrict__ Bbase,
        int* __restrict__ rowptr, int* __restrict__ col, int M, int nBk, int nE) {
    __shared__ int ldeg[256];
    __shared__ int wtot[4];
    const int bk = blockIdx.x;
    const int tid = threadIdx.x;
    const int node0 = bk << 8;
    const int lo = Bbase[bk];
    const int hi = (bk + 1 < nBk) ? Bbase[bk + 1] : nE;

    ldeg[tid] = 0;
    __syncthreads();
    for (int j = lo + tid; j < hi; j += TB)
        atomicAdd(&ldeg[ebuf[j].x & 255], 1);
    __syncthreads();

    // exclusive scan of 256 degrees (wave shfl + cross-wave offsets)
    const int lane = tid & 63, wv = tid >> 6;
    int v = ldeg[tid];
    int x = v;
    #pragma unroll
    for (int off = 1; off < 64; off <<= 1) {
        int y = __shfl_up(x, off);
        if (lane >= off) x += y;
    }
    if (lane == 63) wtot[wv] = x;
    __syncthreads();
    int wbase = 0;
    #pragma unroll
    for (int w = 0; w < 4; ++w) if (w < wv) wbase += wtot[w];
    const int excl = lo + wbase + (x - v);

    const int node = node0 + tid;
    if (node < M) rowptr[node] = excl;
    if (bk == 0 && tid == 0) rowptr[M] = nE;
    __syncthreads();
    ldeg[tid] = excl;   // becomes cursor
    __syncthreads();
    for (int j = lo + tid; j < hi; j += TB) {
        int2 e = ebuf[j];
        int pos = atomicAdd(&ldeg[e.x & 255], 1);
        col[pos] = e.y;
    }
}

// ---------------- f32 -> fp16 conversion -------------------------------------
__global__ void tofp16_kernel(const float4* __restrict__ in, uint2* __restrict__ out, int n4) {
    int t = blockIdx.x * blockDim.x + threadIdx.x;
    if (t >= n4) return;
    float4 v = in[t];
    __half2 a = __floats2half2_rn(v.x, v.y);
    __half2 b = __floats2half2_rn(v.z, v.w);
    out[t] = make_uint2(*(unsigned*)&a, *(unsigned*)&b);
}

// ---------------- fused gather (fp16 payload): out = relu?(sbuf + mean) ------
template<int F>
__global__ __launch_bounds__(TB) void gather_fused_h(
        const uint2* __restrict__ xh, const int* __restrict__ col,
        const int* __restrict__ rowptr,
        const float* __restrict__ sbuf, const float* __restrict__ hcopy,
        float* __restrict__ out, int M, int ldout, int doRelu) {
    constexpr int C4 = F / 4;      // 8-byte chunks per row: 16 (F=64) or 8 (F=32)
    constexpr int ES = 64 / C4;    // edge slices per wave
    const int wave = threadIdx.x >> 6;
    const int lane = threadIdx.x & 63;
    const int node = blockIdx.x * (TB / 64) + wave;
    if (node >= M) return;
    const int c4 = lane & (C4 - 1);
    const int es = lane >> (F == 64 ? 4 : 3);

    const int s = rowptr[node], e = rowptr[node + 1];
    float ax = 0.f, ay = 0.f, az = 0.f, aw = 0.f;
    int j = s + es;
    for (; j + ES < e; j += 2 * ES) {
        int cs0 = col[j];
        int cs1 = col[j + ES];
        uint2 u0 = xh[(size_t)cs0 * C4 + c4];
        uint2 u1 = xh[(size_t)cs1 * C4 + c4];
        float2 f0 = __half22float2(*(__half2*)&u0.x);
        float2 f1 = __half22float2(*(__half2*)&u0.y);
        float2 g0 = __half22float2(*(__half2*)&u1.x);
        float2 g1 = __half22float2(*(__half2*)&u1.y);
        ax += f0.x + g0.x; ay += f0.y + g0.y;
        az += f1.x + g1.x; aw += f1.y + g1.y;
    }
    if (j < e) {
        int cs = col[j];
        uint2 u = xh[(size_t)cs * C4 + c4];
        float2 f0 = __half22float2(*(__half2*)&u.x);
        float2 f1 = __half22float2(*(__half2*)&u.y);
        ax += f0.x; ay += f0.y; az += f1.x; aw += f1.y;
    }
    #pragma unroll
    for (int d = C4; d < 64; d <<= 1) {
        ax += __shfl_xor(ax, d);
        ay += __shfl_xor(ay, d);
        az += __shfl_xor(az, d);
        aw += __shfl_xor(aw, d);
    }
    if (es == 0) {
        const float inv = 1.0f / fmaxf((float)(e - s), 1.0f);
        float4 v = make_float4(ax * inv, ay * inv, az * inv, aw * inv);
        if (sbuf) {
            float4 sv = *(const float4*)(sbuf + (size_t)node * F + 4 * c4);
            v.x += sv.x; v.y += sv.y; v.z += sv.z; v.w += sv.w;
        }
        if (doRelu) {
            v.x = fmaxf(v.x, 0.f); v.y = fmaxf(v.y, 0.f);
            v.z = fmaxf(v.z, 0.f); v.w = fmaxf(v.w, 0.f);
        }
        float* orow = out + (size_t)node * ldout;
        *(float4*)(orow + 4 * c4) = v;
        if (hcopy) {
            float4 hv = *(const float4*)(hcopy + (size_t)node * F + 4 * c4);
            *(float4*)(orow + F + 4 * c4) = hv;
        }
    }
}

// ---------------- LDS-staged dual-OUTPUT GEMM: Yh = fp16(A@Wn); S = A@Ws + b -
// bank-conflict-free: thread's j-th acc maps to column cj[j] (rotated by colg)
template<int K, int N>
__global__ __launch_bounds__(TB) void gemm_dualout_lds(
        const float* __restrict__ A, const float* __restrict__ Wn,
        const float* __restrict__ Ws, const float* __restrict__ bias,
        __half* __restrict__ Yh, float* __restrict__ S, int M) {
    constexpr int C = N / 8;
    constexpr int NC4 = C / 4;
    constexpr int KC0 = 2048 / N;
    constexpr int KC = KC0 < K ? KC0 : K;
    constexpr int P4 = (KC * N) / 1024;

    __shared__ float lwn[KC * N];
    __shared__ float lws[KC * N];

    const int tid = threadIdx.x;
    const int colg = tid & 7;
    const int rowg = tid >> 3;
    const int row0 = blockIdx.x * 64 + rowg * 2;
    const bool valid = row0 < M;
    const int c0 = colg * C;

    int cj[NC4];
    #pragma unroll
    for (int j = 0; j < NC4; ++j) cj[j] = c0 + 4 * ((j + colg) & (NC4 - 1));

    float4 accY[2][NC4], accS[2][NC4];
    #pragma unroll
    for (int r = 0; r < 2; ++r)
        #pragma unroll
        for (int j = 0; j < NC4; ++j) {
            accY[r][j] = make_float4(0.f, 0.f, 0.f, 0.f);
            accS[r][j] = make_float4(0.f, 0.f, 0.f, 0.f);
        }

    for (int kc = 0; kc < K; kc += KC) {
        __syncthreads();
        const float4* gwn = (const float4*)(Wn + (size_t)kc * N);
        const float4* gws = (const float4*)(Ws + (size_t)kc * N);
        #pragma unroll
        for (int i = 0; i < P4; ++i) {
            int f4i = tid + i * 256;
            ((float4*)lwn)[f4i] = gwn[f4i];
            ((float4*)lws)[f4i] = gws[f4i];
        }
        __syncthreads();
        if (valid) {
            const float* a = A + (size_t)row0 * K + kc;
            for (int k = 0; k < KC; k += 4) {
                float4 av[2];
                #pragma unroll
                for (int r = 0; r < 2; ++r)
                    av[r] = *(const float4*)(a + (size_t)r * K + k);
                #pragma unroll
                for (int kk = 0; kk < 4; ++kk) {
                    #pragma unroll
                    for (int j = 0; j < NC4; ++j) {
                        float4 wn = *(const float4*)(&lwn[(k + kk) * N + cj[j]]);
                        float4 ws = *(const float4*)(&lws[(k + kk) * N + cj[j]]);
                        #pragma unroll
                        for (int r = 0; r < 2; ++r) {
                            float ar = ((const float*)&av[r])[kk];
                            accY[r][j].x += ar * wn.x; accY[r][j].y += ar * wn.y;
                            accY[r][j].z += ar * wn.z; accY[r][j].w += ar * wn.w;
                            accS[r][j].x += ar * ws.x; accS[r][j].y += ar * ws.y;
                            accS[r][j].z += ar * ws.z; accS[r][j].w += ar * ws.w;
                        }
                    }
                }
            }
        }
    }

    if (valid) {
        #pragma unroll
        for (int j = 0; j < NC4; ++j) {
            const int c = cj[j];
            float4 bb = *(const float4*)(bias + c);
            #pragma unroll
            for (int r = 0; r < 2; ++r) {
                const int row = row0 + r;
                float4 y = accY[r][j];
                __half2 p0 = __floats2half2_rn(y.x, y.y);
                __half2 p1 = __floats2half2_rn(y.z, y.w);
                *(uint2*)(Yh + (size_t)row * N + c) =
                    make_uint2(*(unsigned*)&p0, *(unsigned*)&p1);
                float4 v = accS[r][j];
                v.x += bb.x; v.y += bb.y; v.z += bb.z; v.w += bb.w;
                *(float4*)(S + (size_t)row * N + c) = v;
            }
        }
    }
}

// ---------------- LDS-staged dual-INPUT GEMM: out = relu(A@W + A2@W2 + b) ----
template<int K, int N>
__global__ __launch_bounds__(TB) void gemm_dualin_lds(
        const float* __restrict__ A, const float* __restrict__ W,
        const float* __restrict__ A2, const float* __restrict__ W2,
        const float* __restrict__ bias, float* __restrict__ out, int M) {
    constexpr int C = N / 8;
    constexpr int NC4 = C / 4;
    constexpr int KC0 = 2048 / N;
    constexpr int KC = KC0 < K ? KC0 : K;
    constexpr int P4 = (KC * N) / 1024;

    __shared__ float lw[KC * N];
    __shared__ float lw2[KC * N];

    const int tid = threadIdx.x;
    const int colg = tid & 7;
    const int rowg = tid >> 3;
    const int row0 = blockIdx.x * 64 + rowg * 2;
    const bool valid = row0 < M;
    const int c0 = colg * C;

    int cj[NC4];
    #pragma unroll
    for (int j = 0; j < NC4; ++j) cj[j] = c0 + 4 * ((j + colg) & (NC4 - 1));

    float4 acc[2][NC4];
    #pragma unroll
    for (int r = 0; r < 2; ++r)
        #pragma unroll
        for (int j = 0; j < NC4; ++j) acc[r][j] = make_float4(0.f, 0.f, 0.f, 0.f);

    for (int kc = 0; kc < K; kc += KC) {
        __syncthreads();
        const float4* gw  = (const float4*)(W  + (size_t)kc * N);
        const float4* gw2 = (const float4*)(W2 + (size_t)kc * N);
        #pragma unroll
        for (int i = 0; i < P4; ++i) {
            int f4i = tid + i * 256;
            ((float4*)lw)[f4i]  = gw[f4i];
            ((float4*)lw2)[f4i] = gw2[f4i];
        }
        __syncthreads();
        if (valid) {
            const float* a  = A  + (size_t)row0 * K + kc;
            const float* a2 = A2 + (size_t)row0 * K + kc;
            for (int k = 0; k < KC; k += 4) {
                float4 av[2], av2[2];
                #pragma unroll
                for (int r = 0; r < 2; ++r) {
                    av[r]  = *(const float4*)(a  + (size_t)r * K + k);
                    av2[r] = *(const float4*)(a2 + (size_t)r * K + k);
                }
                #pragma unroll
                for (int kk = 0; kk < 4; ++kk) {
                    #pragma unroll
                    for (int j = 0; j < NC4; ++j) {
                        float4 wv  = *(const float4*)(&lw[(k + kk) * N + cj[j]]);
                        float4 wv2 = *(const float4*)(&lw2[(k + kk) * N + cj[j]]);
                        #pragma unroll
                        for (int r = 0; r < 2; ++r) {
                            float ar  = ((const float*)&av[r])[kk];
                            float ar2 = ((const float*)&av2[r])[kk];
                            acc[r][j].x += ar * wv.x + ar2 * wv2.x;
                            acc[r][j].y += ar * wv.y + ar2 * wv2.y;
                            acc[r][j].z += ar * wv.z + ar2 * wv2.z;
                            acc[r][j].w += ar * wv.w + ar2 * wv2.w;
                        }
                    }
                }
            }
        }
    }

    if (valid) {
        #pragma unroll
        for (int j = 0; j < NC4; ++j) {
            const int c = cj[j];
            float4 bb = *(const float4*)(bias + c);
            #pragma unroll
            for (int r = 0; r < 2; ++r) {
                float4 v = acc[r][j];
                v.x = fmaxf(v.x + bb.x, 0.f);
                v.y = fmaxf(v.y + bb.y, 0.f);
                v.z = fmaxf(v.z + bb.z, 0.f);
                v.w = fmaxf(v.w + bb.w, 0.f);
                *(float4*)(out + (size_t)(row0 + r) * N + c) = v;
            }
        }
    }
}

// ---------------- host orchestration ----------------------------------------
static inline int cdiv_i(long long a, int b) { return (int)((a + b - 1) / b); }

template<int F>
static void launch_gather(const __half* xh, const int* col, const int* rowptr,
                          const float* sbuf, const float* hcopy,
                          float* out, int M, int ldout, int relu, hipStream_t stream) {
    hipLaunchKernelGGL((gather_fused_h<F>), dim3(cdiv_i(M, TB / 64)), dim3(TB), 0, stream,
                       (const uint2*)xh, col, rowptr, sbuf, hcopy, out, M, ldout, relu);
}

extern "C" void kernel_launch(void* const* d_in, const int* in_sizes, int n_in,
                              void* d_out, int out_size, void* d_ws, size_t ws_size,
                              hipStream_t stream) {
    const float* in_feat = (const float*)d_in[0];
    const void* src = d_in[1];
    const void* dst = d_in[2];
    const float* Ws1 = (const float*)d_in[3];  const float* Wn1 = (const float*)d_in[4];  const float* b1 = (const float*)d_in[5];
    const float* Ws2 = (const float*)d_in[6];  const float* Wn2 = (const float*)d_in[7];  const float* b2 = (const float*)d_in[8];
    const float* Ws3 = (const float*)d_in[9];  const float* Wn3 = (const float*)d_in[10]; const float* b3 = (const float*)d_in[11];
    const float* Ws4 = (const float*)d_in[12]; const float* Wn4 = (const float*)d_in[13]; const float* b4 = (const float*)d_in[14];
    const float* Ws5 = (const float*)d_in[15]; const float* Wn5 = (const float*)d_in[16]; const float* b5 = (const float*)d_in[17];
    const float* Ws6 = (const float*)d_in[18]; const float* Wn6 = (const float*)d_in[19]; const float* b6 = (const float*)d_in[20];

    const int M  = in_sizes[0] / 64;   // 100000 nodes
    const int nE = in_sizes[1];        // 1600000 edges
    const int nBk = cdiv_i(M, 256);    // coarse buckets (391)
    const int EC  = cdiv_i(nE, NBLK_P);

    // workspace layout
    float* ws    = (float*)d_ws;
    float* P1    = ws;                       // M*128
    float* P2    = P1 + (size_t)M * 128;     // M*64
    float* P3    = P2 + (size_t)M * 64;      // M*32
    float* sbuf  = P3 + (size_t)M * 32;      // M*64
    float* ybuf  = sbuf + (size_t)M * 64;    // M*64 (layer-1 f32 agg; aliased ebuf in build)
    __half* yh   = (__half*)(ybuf + (size_t)M * 64);  // M*64 halves
    int* rowptr  = (int*)((float*)yh + (size_t)M * 32);  // M+1
    int* col     = rowptr + (M + 1);         // nE
    int* T       = col + nE;                 // NBK
    int* Bbase   = T + NBK;                  // NBK
    int* flag    = Bbase + NBK;              // 1
    int* H       = flag + 1;                 // NBLK_P * NBK
    int2* ebuf   = (int2*)ybuf;              // nE int2 (build only)
    __half* xh   = yh;                       // fp16 in_feat (until layer-2 GEMM)

    // ---- CSR build (counting sort; no global atomics)
    hipLaunchKernelGGL(detect_idx_kernel, dim3(1), dim3(TB), 0, stream,
                       (const int*)src, (const int*)dst, nE, flag);
    hipLaunchKernelGGL(passA_kernel, dim3(NBLK_P), dim3(TB), 0, stream,
                       dst, flag, H, nE, EC, nBk);
    hipLaunchKernelGGL(colscan_kernel, dim3(cdiv_i(nBk, TB)), dim3(TB), 0, stream,
                       H, T, nBk);
    hipLaunchKernelGGL(bucket_scan_kernel, dim3(1), dim3(512), 0, stream, T, Bbase, nBk);
    hipLaunchKernelGGL(passB_kernel, dim3(NBLK_P), dim3(TB), 0, stream,
                       src, dst, flag, H, Bbase, ebuf, nE, EC, nBk);
    hipLaunchKernelGGL(bucket_build_kernel, dim3(nBk), dim3(TB), 0, stream,
                       ebuf, Bbase, rowptr, col, M, nBk, nE);

    // fp16 copy of in_feat for the layer-1 gather
    hipLaunchKernelGGL(tofp16_kernel, dim3(cdiv_i((long long)M * 16, TB)), dim3(TB), 0, stream,
                       (const float4*)in_feat, (uint2*)xh, M * 16);

    const int gblocks = cdiv_i(M, 64);

    // ---- layer 1: 64 -> 128, relu.  ybuf = mean_nbr(in_feat); dual-input GEMM
    launch_gather<64>(xh, col, rowptr, nullptr, nullptr, ybuf, M, 64, 0, stream);
    hipLaunchKernelGGL((gemm_dualin_lds<64, 128>), dim3(gblocks), dim3(TB), 0, stream,
                       in_feat, Ws1, ybuf, Wn1, b1, P1, M);

    // ---- layer 2: 128 -> 64, relu
    hipLaunchKernelGGL((gemm_dualout_lds<128, 64>), dim3(gblocks), dim3(TB), 0, stream,
                       P1, Wn2, Ws2, b2, yh, sbuf, M);
    launch_gather<64>(yh, col, rowptr, sbuf, nullptr, P2, M, 64, 1, stream);

    // ---- layer 3: 64 -> 32, relu
    hipLaunchKernelGGL((gemm_dualout_lds<64, 32>), dim3(gblocks), dim3(TB), 0, stream,
                       P2, Wn3, Ws3, b3, yh, sbuf, M);
    launch_gather<32>(yh, col, rowptr, sbuf, nullptr, P3, M, 32, 1, stream);

    // ---- layer 4: 32 -> 32, relu, concat h3 -> h4 (64 wide) in P2
    hipLaunchKernelGGL((gemm_dualout_lds<32, 32>), dim3(gblocks), dim3(TB), 0, stream,
                       P3, Wn4, Ws4, b4, yh, sbuf, M);
    launch_gather<32>(yh, col, rowptr, sbuf, P3, P2, M, 64, 1, stream);

    // ---- layer 5: 64 -> 64, relu, concat h4 -> h5 (128 wide) in P1
    hipLaunchKernelGGL((gemm_dualout_lds<64, 64>), dim3(gblocks), dim3(TB), 0, stream,
                       P2, Wn5, Ws5, b5, yh, sbuf, M);
    launch_gather<64>(yh, col, rowptr, sbuf, P2, P1, M, 128, 1, stream);

    // ---- layer 6: 128 -> 64, no relu, to d_out
    hipLaunchKernelGGL((gemm_dualout_lds<128, 64>), dim3(gblocks), dim3(TB), 0, stream,
                       P1, Wn6, Ws6, b6, yh, sbuf, M);
    launch_gather<64>(yh, col, rowptr, sbuf, nullptr, (float*)d_out, M, 64, 0, stream);
}

// Round 10
// 601.477 us; speedup vs baseline: 2.8900x; 1.0058x over previous
//
#include <hip/hip_runtime.h>
#include <hip/hip_fp16.h>

#define TB 256
#define NBK 512     // bucket array capacity (actual buckets = cdiv(M,256) <= 512)
#define NBLK_P 128  // partition blocks (H-matrix rows)

// ---------------- index-width detection (int32 vs int64 src/dst) -------------
__global__ void detect_idx_kernel(const int* __restrict__ s32, const int* __restrict__ d32,
                                  int nE, int* __restrict__ flag) {
    __shared__ int nz;
    if (threadIdx.x == 0) nz = 0;
    __syncthreads();
    int n = nE < 2048 ? nE : 2048;
    int local = 0;
    for (int i = threadIdx.x; i < n; i += blockDim.x) {
        if (s32[2 * i + 1] != 0 || d32[2 * i + 1] != 0) local = 1;
    }
    if (local) atomicOr(&nz, 1);
    __syncthreads();
    if (threadIdx.x == 0) *flag = (nz == 0) ? 1 : 0;   // 1 => indices are int64
}

__device__ __forceinline__ int load_idx(const void* p, int e, int is64) {
    return is64 ? (int)((const long long*)p)[e] : ((const int*)p)[e];
}

// ---------------- LDS column swizzle (bank-conflict-free W reads) -------------
// store W[k][c] at k*N + swz<N>(c); read pattern c = colg*(N/8) + 4j then hits
// 8 distinct bank quads across the 8 colgroups (bijective GF(2) map).
template<int N>
__device__ __forceinline__ int swz(int c) {
    if constexpr (N >= 64) {
        constexpr int LOG2C = (N == 128) ? 4 : 3;
        return c ^ (((c >> LOG2C) & 7) << 2);
    } else {
        return c;   // N=32: colg*4 already spans 8 distinct quads
    }
}

// ---------------- CSR build: contention-free counting sort -------------------
__global__ __launch_bounds__(TB) void passA_kernel(
        const void* __restrict__ dst, const int* __restrict__ flag,
        int* __restrict__ H, int nE, int EC, int nBk) {
    __shared__ int lh[NBK];
    for (int i = threadIdx.x; i < NBK; i += TB) lh[i] = 0;
    __syncthreads();
    const int is64 = *flag;
    const int lo = blockIdx.x * EC;
    const int hi = min(nE, lo + EC);
    for (int j = lo + threadIdx.x; j < hi; j += TB) {
        int d = load_idx(dst, j, is64);
        atomicAdd(&lh[d >> 8], 1);
    }
    __syncthreads();
    for (int i = threadIdx.x; i < nBk; i += TB) H[blockIdx.x * nBk + i] = lh[i];
}

__global__ __launch_bounds__(TB) void colscan_kernel(int* __restrict__ H,
                                                     int* __restrict__ T, int nBk) {
    int t = blockIdx.x * blockDim.x + threadIdx.x;
    if (t >= nBk) return;
    int run = 0;
    for (int b = 0; b < NBLK_P; ++b) {
        int v = H[b * nBk + t];
        H[b * nBk + t] = run;
        run += v;
    }
    T[t] = run;
}

__global__ __launch_bounds__(512) void bucket_scan_kernel(const int* __restrict__ hb,
                                                          int* __restrict__ bcur, int nBk) {
    __shared__ int sh[512];
    const int tid = threadIdx.x;
    int v = (tid < nBk) ? hb[tid] : 0;
    sh[tid] = v;
    __syncthreads();
    for (int off = 1; off < 512; off <<= 1) {
        int t = (tid >= off) ? sh[tid - off] : 0;
        __syncthreads();
        sh[tid] += t;
        __syncthreads();
    }
    if (tid < nBk) bcur[tid] = sh[tid] - v;   // exclusive
}

__global__ __launch_bounds__(TB) void passB_kernel(
        const void* __restrict__ src, const void* __restrict__ dst,
        const int* __restrict__ flag, const int* __restrict__ H,
        const int* __restrict__ Bbase, int2* __restrict__ ebuf,
        int nE, int EC, int nBk) {
    __shared__ int lbase[NBK];
    __shared__ int lcur[NBK];
    for (int i = threadIdx.x; i < nBk; i += TB) {
        lbase[i] = Bbase[i] + H[blockIdx.x * nBk + i];
        lcur[i] = 0;
    }
    __syncthreads();
    const int is64 = *flag;
    const int lo = blockIdx.x * EC;
    const int hi = min(nE, lo + EC);
    for (int j = lo + threadIdx.x; j < hi; j += TB) {
        int d = load_idx(dst, j, is64);
        int s = load_idx(src, j, is64);
        int bk = d >> 8;
        int p = lbase[bk] + atomicAdd(&lcur[bk], 1);
        ebuf[p] = make_int2(d, s);
    }
}

__global__ __launch_bounds__(TB) void bucket_build_kernel(
        const int2* __restrict__ ebuf, const int* __restrict__ Bbase,
        int* __restrict__ rowptr, int* __restrict__ col, int M, int nBk, int nE) {
    __shared__ int ldeg[256];
    __shared__ int wtot[4];
    const int bk = blockIdx.x;
    const int tid = threadIdx.x;
    const int node0 = bk << 8;
    const int lo = Bbase[bk];
    const int hi = (bk + 1 < nBk) ? Bbase[bk + 1] : nE;

    ldeg[tid] = 0;
    __syncthreads();
    for (int j = lo + tid; j < hi; j += TB)
        atomicAdd(&ldeg[ebuf[j].x & 255], 1);
    __syncthreads();

    const int lane = tid & 63, wv = tid >> 6;
    int v = ldeg[tid];
    int x = v;
    #pragma unroll
    for (int off = 1; off < 64; off <<= 1) {
        int y = __shfl_up(x, off);
        if (lane >= off) x += y;
    }
    if (lane == 63) wtot[wv] = x;
    __syncthreads();
    int wbase = 0;
    #pragma unroll
    for (int w = 0; w < 4; ++w) if (w < wv) wbase += wtot[w];
    const int excl = lo + wbase + (x - v);

    const int node = node0 + tid;
    if (node < M) rowptr[node] = excl;
    if (bk == 0 && tid == 0) rowptr[M] = nE;
    __syncthreads();
    ldeg[tid] = excl;   // becomes cursor
    __syncthreads();
    for (int j = lo + tid; j < hi; j += TB) {
        int2 e = ebuf[j];
        int pos = atomicAdd(&ldeg[e.x & 255], 1);
        col[pos] = e.y;
    }
}

// ---------------- f32 -> fp16 conversion -------------------------------------
__global__ void tofp16_kernel(const float4* __restrict__ in, uint2* __restrict__ out, int n4) {
    int t = blockIdx.x * blockDim.x + threadIdx.x;
    if (t >= n4) return;
    float4 v = in[t];
    __half2 a = __floats2half2_rn(v.x, v.y);
    __half2 b = __floats2half2_rn(v.z, v.w);
    out[t] = make_uint2(*(unsigned*)&a, *(unsigned*)&b);
}

// ---------------- fused gather (fp16 payload): out = relu?(sbuf + mean) ------
template<int F>
__global__ __launch_bounds__(TB) void gather_fused_h(
        const uint2* __restrict__ xh, const int* __restrict__ col,
        const int* __restrict__ rowptr,
        const float* __restrict__ sbuf, const float* __restrict__ hcopy,
        float* __restrict__ out, int M, int ldout, int doRelu) {
    constexpr int C4 = F / 4;      // 8-byte chunks per row: 16 (F=64) or 8 (F=32)
    constexpr int ES = 64 / C4;    // edge slices per wave
    const int wave = threadIdx.x >> 6;
    const int lane = threadIdx.x & 63;
    const int node = blockIdx.x * (TB / 64) + wave;
    if (node >= M) return;
    const int c4 = lane & (C4 - 1);
    const int es = lane >> (F == 64 ? 4 : 3);

    const int s = rowptr[node], e = rowptr[node + 1];
    float ax = 0.f, ay = 0.f, az = 0.f, aw = 0.f;
    int j = s + es;
    for (; j + ES < e; j += 2 * ES) {
        int cs0 = col[j];
        int cs1 = col[j + ES];
        uint2 u0 = xh[(size_t)cs0 * C4 + c4];
        uint2 u1 = xh[(size_t)cs1 * C4 + c4];
        float2 f0 = __half22float2(*(__half2*)&u0.x);
        float2 f1 = __half22float2(*(__half2*)&u0.y);
        float2 g0 = __half22float2(*(__half2*)&u1.x);
        float2 g1 = __half22float2(*(__half2*)&u1.y);
        ax += f0.x + g0.x; ay += f0.y + g0.y;
        az += f1.x + g1.x; aw += f1.y + g1.y;
    }
    if (j < e) {
        int cs = col[j];
        uint2 u = xh[(size_t)cs * C4 + c4];
        float2 f0 = __half22float2(*(__half2*)&u.x);
        float2 f1 = __half22float2(*(__half2*)&u.y);
        ax += f0.x; ay += f0.y; az += f1.x; aw += f1.y;
    }
    #pragma unroll
    for (int d = C4; d < 64; d <<= 1) {
        ax += __shfl_xor(ax, d);
        ay += __shfl_xor(ay, d);
        az += __shfl_xor(az, d);
        aw += __shfl_xor(aw, d);
    }
    if (es == 0) {
        const float inv = 1.0f / fmaxf((float)(e - s), 1.0f);
        float4 v = make_float4(ax * inv, ay * inv, az * inv, aw * inv);
        if (sbuf) {
            float4 sv = *(const float4*)(sbuf + (size_t)node * F + 4 * c4);
            v.x += sv.x; v.y += sv.y; v.z += sv.z; v.w += sv.w;
        }
        if (doRelu) {
            v.x = fmaxf(v.x, 0.f); v.y = fmaxf(v.y, 0.f);
            v.z = fmaxf(v.z, 0.f); v.w = fmaxf(v.w, 0.f);
        }
        float* orow = out + (size_t)node * ldout;
        *(float4*)(orow + 4 * c4) = v;
        if (hcopy) {
            float4 hv = *(const float4*)(hcopy + (size_t)node * F + 4 * c4);
            *(float4*)(orow + F + 4 * c4) = hv;
        }
    }
}

// ---------------- LDS-staged dual-OUTPUT GEMM: Yh = fp16(A@Wn); S = A@Ws + b -
template<int K, int N>
__global__ __launch_bounds__(TB) void gemm_dualout_lds(
        const float* __restrict__ A, const float* __restrict__ Wn,
        const float* __restrict__ Ws, const float* __restrict__ bias,
        __half* __restrict__ Yh, float* __restrict__ S, int M) {
    constexpr int C = N / 8;
    constexpr int NC4 = C / 4;
    constexpr int KC0 = 2048 / N;
    constexpr int KC = KC0 < K ? KC0 : K;
    constexpr int P4 = (KC * N) / 1024;

    __shared__ float lwn[KC * N];
    __shared__ float lws[KC * N];

    const int tid = threadIdx.x;
    const int colg = tid & 7;
    const int rowg = tid >> 3;
    const int row0 = blockIdx.x * 64 + rowg * 2;
    const bool valid = row0 < M;
    const int c0 = colg * C;

    int scj[NC4];
    #pragma unroll
    for (int j = 0; j < NC4; ++j) scj[j] = swz<N>(c0 + 4 * j);

    float4 accY[2][NC4], accS[2][NC4];
    #pragma unroll
    for (int r = 0; r < 2; ++r)
        #pragma unroll
        for (int j = 0; j < NC4; ++j) {
            accY[r][j] = make_float4(0.f, 0.f, 0.f, 0.f);
            accS[r][j] = make_float4(0.f, 0.f, 0.f, 0.f);
        }

    for (int kc = 0; kc < K; kc += KC) {
        __syncthreads();
        const float4* gwn = (const float4*)(Wn + (size_t)kc * N);
        const float4* gws = (const float4*)(Ws + (size_t)kc * N);
        #pragma unroll
        for (int i = 0; i < P4; ++i) {
            int f4i = tid + i * 256;
            int kr = (f4i << 2) / N;
            int c  = (f4i << 2) & (N - 1);
            int p  = kr * N + swz<N>(c);
            *(float4*)(&lwn[p]) = gwn[f4i];
            *(float4*)(&lws[p]) = gws[f4i];
        }
        __syncthreads();
        if (valid) {
            const float* a = A + (size_t)row0 * K + kc;
            for (int k = 0; k < KC; k += 4) {
                float4 av[2];
                #pragma unroll
                for (int r = 0; r < 2; ++r)
                    av[r] = *(const float4*)(a + (size_t)r * K + k);
                #pragma unroll
                for (int kk = 0; kk < 4; ++kk) {
                    #pragma unroll
                    for (int j = 0; j < NC4; ++j) {
                        float4 wn = *(const float4*)(&lwn[(k + kk) * N + scj[j]]);
                        float4 ws = *(const float4*)(&lws[(k + kk) * N + scj[j]]);
                        #pragma unroll
                        for (int r = 0; r < 2; ++r) {
                            float ar = ((const float*)&av[r])[kk];
                            accY[r][j].x += ar * wn.x; accY[r][j].y += ar * wn.y;
                            accY[r][j].z += ar * wn.z; accY[r][j].w += ar * wn.w;
                            accS[r][j].x += ar * ws.x; accS[r][j].y += ar * ws.y;
                            accS[r][j].z += ar * ws.z; accS[r][j].w += ar * ws.w;
                        }
                    }
                }
            }
        }
    }

    if (valid) {
        #pragma unroll
        for (int j = 0; j < NC4; ++j) {
            const int c = c0 + 4 * j;
            float4 bb = *(const float4*)(bias + c);
            #pragma unroll
            for (int r = 0; r < 2; ++r) {
                const int row = row0 + r;
                float4 y = accY[r][j];
                __half2 p0 = __floats2half2_rn(y.x, y.y);
                __half2 p1 = __floats2half2_rn(y.z, y.w);
                *(uint2*)(Yh + (size_t)row * N + c) =
                    make_uint2(*(unsigned*)&p0, *(unsigned*)&p1);
                float4 v = accS[r][j];
                v.x += bb.x; v.y += bb.y; v.z += bb.z; v.w += bb.w;
                *(float4*)(S + (size_t)row * N + c) = v;
            }
        }
    }
}

// ---------------- LDS-staged dual-INPUT GEMM: out = relu(A@W + A2@W2 + b) ----
template<int K, int N>
__global__ __launch_bounds__(TB) void gemm_dualin_lds(
        const float* __restrict__ A, const float* __restrict__ W,
        const float* __restrict__ A2, const float* __restrict__ W2,
        const float* __restrict__ bias, float* __restrict__ out, int M) {
    constexpr int C = N / 8;
    constexpr int NC4 = C / 4;
    constexpr int KC0 = 2048 / N;
    constexpr int KC = KC0 < K ? KC0 : K;
    constexpr int P4 = (KC * N) / 1024;

    __shared__ float lw[KC * N];
    __shared__ float lw2[KC * N];

    const int tid = threadIdx.x;
    const int colg = tid & 7;
    const int rowg = tid >> 3;
    const int row0 = blockIdx.x * 64 + rowg * 2;
    const bool valid = row0 < M;
    const int c0 = colg * C;

    int scj[NC4];
    #pragma unroll
    for (int j = 0; j < NC4; ++j) scj[j] = swz<N>(c0 + 4 * j);

    float4 acc[2][NC4];
    #pragma unroll
    for (int r = 0; r < 2; ++r)
        #pragma unroll
        for (int j = 0; j < NC4; ++j) acc[r][j] = make_float4(0.f, 0.f, 0.f, 0.f);

    for (int kc = 0; kc < K; kc += KC) {
        __syncthreads();
        const float4* gw  = (const float4*)(W  + (size_t)kc * N);
        const float4* gw2 = (const float4*)(W2 + (size_t)kc * N);
        #pragma unroll
        for (int i = 0; i < P4; ++i) {
            int f4i = tid + i * 256;
            int kr = (f4i << 2) / N;
            int c  = (f4i << 2) & (N - 1);
            int p  = kr * N + swz<N>(c);
            *(float4*)(&lw[p])  = gw[f4i];
            *(float4*)(&lw2[p]) = gw2[f4i];
        }
        __syncthreads();
        if (valid) {
            const float* a  = A  + (size_t)row0 * K + kc;
            const float* a2 = A2 + (size_t)row0 * K + kc;
            for (int k = 0; k < KC; k += 4) {
                float4 av[2], av2[2];
                #pragma unroll
                for (int r = 0; r < 2; ++r) {
                    av[r]  = *(const float4*)(a  + (size_t)r * K + k);
                    av2[r] = *(const float4*)(a2 + (size_t)r * K + k);
                }
                #pragma unroll
                for (int kk = 0; kk < 4; ++kk) {
                    #pragma unroll
                    for (int j = 0; j < NC4; ++j) {
                        float4 wv  = *(const float4*)(&lw[(k + kk) * N + scj[j]]);
                        float4 wv2 = *(const float4*)(&lw2[(k + kk) * N + scj[j]]);
                        #pragma unroll
                        for (int r = 0; r < 2; ++r) {
                            float ar  = ((const float*)&av[r])[kk];
                            float ar2 = ((const float*)&av2[r])[kk];
                            acc[r][j].x += ar * wv.x + ar2 * wv2.x;
                            acc[r][j].y += ar * wv.y + ar2 * wv2.y;
                            acc[r][j].z += ar * wv.z + ar2 * wv2.z;
                            acc[r][j].w += ar * wv.w + ar2 * wv2.w;
                        }
                    }
                }
            }
        }
    }

    if (valid) {
        #pragma unroll
        for (int j = 0; j < NC4; ++j) {
            const int c = c0 + 4 * j;
            float4 bb = *(const float4*)(bias + c);
            #pragma unroll
            for (int r = 0; r < 2; ++r) {
                float4 v = acc[r][j];
                v.x = fmaxf(v.x + bb.x, 0.f);
                v.y = fmaxf(v.y + bb.y, 0.f);
                v.z = fmaxf(v.z + bb.z, 0.f);
                v.w = fmaxf(v.w + bb.w, 0.f);
                *(float4*)(out + (size_t)(row0 + r) * N + c) = v;
            }
        }
    }
}

// ---------------- host orchestration ----------------------------------------
static inline int cdiv_i(long long a, int b) { return (int)((a + b - 1) / b); }

template<int F>
static void launch_gather(const __half* xh, const int* col, const int* rowptr,
                          const float* sbuf, const float* hcopy,
                          float* out, int M, int ldout, int relu, hipStream_t stream) {
    hipLaunchKernelGGL((gather_fused_h<F>), dim3(cdiv_i(M, TB / 64)), dim3(TB), 0, stream,
                       (const uint2*)xh, col, rowptr, sbuf, hcopy, out, M, ldout, relu);
}

extern "C" void kernel_launch(void* const* d_in, const int* in_sizes, int n_in,
                              void* d_out, int out_size, void* d_ws, size_t ws_size,
                              hipStream_t stream) {
    const float* in_feat = (const float*)d_in[0];
    const void* src = d_in[1];
    const void* dst = d_in[2];
    const float* Ws1 = (const float*)d_in[3];  const float* Wn1 = (const float*)d_in[4];  const float* b1 = (const float*)d_in[5];
    const float* Ws2 = (const float*)d_in[6];  const float* Wn2 = (const float*)d_in[7];  const float* b2 = (const float*)d_in[8];
    const float* Ws3 = (const float*)d_in[9];  const float* Wn3 = (const float*)d_in[10]; const float* b3 = (const float*)d_in[11];
    const float* Ws4 = (const float*)d_in[12]; const float* Wn4 = (const float*)d_in[13]; const float* b4 = (const float*)d_in[14];
    const float* Ws5 = (const float*)d_in[15]; const float* Wn5 = (const float*)d_in[16]; const float* b5 = (const float*)d_in[17];
    const float* Ws6 = (const float*)d_in[18]; const float* Wn6 = (const float*)d_in[19]; const float* b6 = (const float*)d_in[20];

    const int M  = in_sizes[0] / 64;   // 100000 nodes
    const int nE = in_sizes[1];        // 1600000 edges
    const int nBk = cdiv_i(M, 256);    // coarse buckets (391)
    const int EC  = cdiv_i(nE, NBLK_P);

    // workspace layout
    float* ws    = (float*)d_ws;
    float* P1    = ws;                       // M*128
    float* P2    = P1 + (size_t)M * 128;     // M*64
    float* P3    = P2 + (size_t)M * 64;      // M*32
    float* sbuf  = P3 + (size_t)M * 32;      // M*64
    float* ybuf  = sbuf + (size_t)M * 64;    // M*64 (layer-1 f32 agg; aliased ebuf in build)
    __half* yh   = (__half*)(ybuf + (size_t)M * 64);  // M*64 halves
    int* rowptr  = (int*)((float*)yh + (size_t)M * 32);  // M+1
    int* col     = rowptr + (M + 1);         // nE
    int* T       = col + nE;                 // NBK
    int* Bbase   = T + NBK;                  // NBK
    int* flag    = Bbase + NBK;              // 1
    int* H       = flag + 1;                 // NBLK_P * NBK
    int2* ebuf   = (int2*)ybuf;              // nE int2 (build only)
    __half* xh   = yh;                       // fp16 in_feat (until layer-2 GEMM)

    // ---- CSR build (counting sort; no global atomics)
    hipLaunchKernelGGL(detect_idx_kernel, dim3(1), dim3(TB), 0, stream,
                       (const int*)src, (const int*)dst, nE, flag);
    hipLaunchKernelGGL(passA_kernel, dim3(NBLK_P), dim3(TB), 0, stream,
                       dst, flag, H, nE, EC, nBk);
    hipLaunchKernelGGL(colscan_kernel, dim3(cdiv_i(nBk, TB)), dim3(TB), 0, stream,
                       H, T, nBk);
    hipLaunchKernelGGL(bucket_scan_kernel, dim3(1), dim3(512), 0, stream, T, Bbase, nBk);
    hipLaunchKernelGGL(passB_kernel, dim3(NBLK_P), dim3(TB), 0, stream,
                       src, dst, flag, H, Bbase, ebuf, nE, EC, nBk);
    hipLaunchKernelGGL(bucket_build_kernel, dim3(nBk), dim3(TB), 0, stream,
                       ebuf, Bbase, rowptr, col, M, nBk, nE);

    // fp16 copy of in_feat for the layer-1 gather
    hipLaunchKernelGGL(tofp16_kernel, dim3(cdiv_i((long long)M * 16, TB)), dim3(TB), 0, stream,
                       (const float4*)in_feat, (uint2*)xh, M * 16);

    const int gblocks = cdiv_i(M, 64);

    // ---- layer 1: 64 -> 128, relu.  ybuf = mean_nbr(in_feat); dual-input GEMM
    launch_gather<64>(xh, col, rowptr, nullptr, nullptr, ybuf, M, 64, 0, stream);
    hipLaunchKernelGGL((gemm_dualin_lds<64, 128>), dim3(gblocks), dim3(TB), 0, stream,
                       in_feat, Ws1, ybuf, Wn1, b1, P1, M);

    // ---- layer 2: 128 -> 64, relu
    hipLaunchKernelGGL((gemm_dualout_lds<128, 64>), dim3(gblocks), dim3(TB), 0, stream,
                       P1, Wn2, Ws2, b2, yh, sbuf, M);
    launch_gather<64>(yh, col, rowptr, sbuf, nullptr, P2, M, 64, 1, stream);

    // ---- layer 3: 64 -> 32, relu
    hipLaunchKernelGGL((gemm_dualout_lds<64, 32>), dim3(gblocks), dim3(TB), 0, stream,
                       P2, Wn3, Ws3, b3, yh, sbuf, M);
    launch_gather<32>(yh, col, rowptr, sbuf, nullptr, P3, M, 32, 1, stream);

    // ---- layer 4: 32 -> 32, relu, concat h3 -> h4 (64 wide) in P2
    hipLaunchKernelGGL((gemm_dualout_lds<32, 32>), dim3(gblocks), dim3(TB), 0, stream,
                       P3, Wn4, Ws4, b4, yh, sbuf, M);
    launch_gather<32>(yh, col, rowptr, sbuf, P3, P2, M, 64, 1, stream);

    // ---- layer 5: 64 -> 64, relu, concat h4 -> h5 (128 wide) in P1
    hipLaunchKernelGGL((gemm_dualout_lds<64, 64>), dim3(gblocks), dim3(TB), 0, stream,
                       P2, Wn5, Ws5, b5, yh, sbuf, M);
    launch_gather<64>(yh, col, rowptr, sbuf, P2, P1, M, 128, 1, stream);

    // ---- layer 6: 128 -> 64, no relu, to d_out
    hipLaunchKernelGGL((gemm_dualout_lds<128, 64>), dim3(gblocks), dim3(TB), 0, stream,
                       P1, Wn6, Ws6, b6, yh, sbuf, M);
    launch_gather<64>(yh, col, rowptr, sbuf, nullptr, (float*)d_out, M, 64, 0, stream);
}

// Round 11
// 458.481 us; speedup vs baseline: 3.7914x; 1.3119x over previous
//
#include <hip/hip_runtime.h>
#include <hip/hip_fp16.h>

#define TB 256
#define NBK 512     // bucket array capacity (actual buckets = cdiv(M,256) <= 512)
#define NBLK_P 128  // partition blocks (H-matrix rows)

typedef _Float16 f16;
typedef __attribute__((ext_vector_type(8))) _Float16 f16x8;
typedef __attribute__((ext_vector_type(4))) float f32x4;

__device__ __forceinline__ f32x4 mfma16(f16x8 a, f16x8 b, f32x4 c) {
    return __builtin_amdgcn_mfma_f32_16x16x32_f16(a, b, c, 0, 0, 0);
}

// ---------------- index-width detection (int32 vs int64 src/dst) -------------
__global__ void detect_idx_kernel(const int* __restrict__ s32, const int* __restrict__ d32,
                                  int nE, int* __restrict__ flag) {
    __shared__ int nz;
    if (threadIdx.x == 0) nz = 0;
    __syncthreads();
    int n = nE < 2048 ? nE : 2048;
    int local = 0;
    for (int i = threadIdx.x; i < n; i += blockDim.x) {
        if (s32[2 * i + 1] != 0 || d32[2 * i + 1] != 0) local = 1;
    }
    if (local) atomicOr(&nz, 1);
    __syncthreads();
    if (threadIdx.x == 0) *flag = (nz == 0) ? 1 : 0;   // 1 => indices are int64
}

__device__ __forceinline__ int load_idx(const void* p, int e, int is64) {
    return is64 ? (int)((const long long*)p)[e] : ((const int*)p)[e];
}

// ---------------- CSR build: contention-free counting sort -------------------
__global__ __launch_bounds__(TB) void passA_kernel(
        const void* __restrict__ dst, const int* __restrict__ flag,
        int* __restrict__ H, int nE, int EC, int nBk) {
    __shared__ int lh[NBK];
    for (int i = threadIdx.x; i < NBK; i += TB) lh[i] = 0;
    __syncthreads();
    const int is64 = *flag;
    const int lo = blockIdx.x * EC;
    const int hi = min(nE, lo + EC);
    for (int j = lo + threadIdx.x; j < hi; j += TB) {
        int d = load_idx(dst, j, is64);
        atomicAdd(&lh[d >> 8], 1);
    }
    __syncthreads();
    for (int i = threadIdx.x; i < nBk; i += TB) H[blockIdx.x * nBk + i] = lh[i];
}

__global__ __launch_bounds__(TB) void colscan_kernel(int* __restrict__ H,
                                                     int* __restrict__ T, int nBk) {
    int t = blockIdx.x * blockDim.x + threadIdx.x;
    if (t >= nBk) return;
    int run = 0;
    for (int b = 0; b < NBLK_P; ++b) {
        int v = H[b * nBk + t];
        H[b * nBk + t] = run;
        run += v;
    }
    T[t] = run;
}

__global__ __launch_bounds__(512) void bucket_scan_kernel(const int* __restrict__ hb,
                                                          int* __restrict__ bcur, int nBk) {
    __shared__ int sh[512];
    const int tid = threadIdx.x;
    int v = (tid < nBk) ? hb[tid] : 0;
    sh[tid] = v;
    __syncthreads();
    for (int off = 1; off < 512; off <<= 1) {
        int t = (tid >= off) ? sh[tid - off] : 0;
        __syncthreads();
        sh[tid] += t;
        __syncthreads();
    }
    if (tid < nBk) bcur[tid] = sh[tid] - v;   // exclusive
}

__global__ __launch_bounds__(TB) void passB_kernel(
        const void* __restrict__ src, const void* __restrict__ dst,
        const int* __restrict__ flag, const int* __restrict__ H,
        const int* __restrict__ Bbase, int2* __restrict__ ebuf,
        int nE, int EC, int nBk) {
    __shared__ int lbase[NBK];
    __shared__ int lcur[NBK];
    for (int i = threadIdx.x; i < nBk; i += TB) {
        lbase[i] = Bbase[i] + H[blockIdx.x * nBk + i];
        lcur[i] = 0;
    }
    __syncthreads();
    const int is64 = *flag;
    const int lo = blockIdx.x * EC;
    const int hi = min(nE, lo + EC);
    for (int j = lo + threadIdx.x; j < hi; j += TB) {
        int d = load_idx(dst, j, is64);
        int s = load_idx(src, j, is64);
        int bk = d >> 8;
        int p = lbase[bk] + atomicAdd(&lcur[bk], 1);
        ebuf[p] = make_int2(d, s);
    }
}

__global__ __launch_bounds__(TB) void bucket_build_kernel(
        const int2* __restrict__ ebuf, const int* __restrict__ Bbase,
        int* __restrict__ rowptr, int* __restrict__ col, int M, int nBk, int nE) {
    __shared__ int ldeg[256];
    __shared__ int wtot[4];
    const int bk = blockIdx.x;
    const int tid = threadIdx.x;
    const int node0 = bk << 8;
    const int lo = Bbase[bk];
    const int hi = (bk + 1 < nBk) ? Bbase[bk + 1] : nE;

    ldeg[tid] = 0;
    __syncthreads();
    for (int j = lo + tid; j < hi; j += TB)
        atomicAdd(&ldeg[ebuf[j].x & 255], 1);
    __syncthreads();

    const int lane = tid & 63, wv = tid >> 6;
    int v = ldeg[tid];
    int x = v;
    #pragma unroll
    for (int off = 1; off < 64; off <<= 1) {
        int y = __shfl_up(x, off);
        if (lane >= off) x += y;
    }
    if (lane == 63) wtot[wv] = x;
    __syncthreads();
    int wbase = 0;
    #pragma unroll
    for (int w = 0; w < 4; ++w) if (w < wv) wbase += wtot[w];
    const int excl = lo + wbase + (x - v);

    const int node = node0 + tid;
    if (node < M) rowptr[node] = excl;
    if (bk == 0 && tid == 0) rowptr[M] = nE;
    __syncthreads();
    ldeg[tid] = excl;   // becomes cursor
    __syncthreads();
    for (int j = lo + tid; j < hi; j += TB) {
        int2 e = ebuf[j];
        int pos = atomicAdd(&ldeg[e.x & 255], 1);
        col[pos] = e.y;
    }
}

// ---------------- f32 -> fp16 conversion -------------------------------------
__global__ void tofp16_kernel(const float4* __restrict__ in, uint2* __restrict__ out, int n4) {
    int t = blockIdx.x * blockDim.x + threadIdx.x;
    if (t >= n4) return;
    float4 v = in[t];
    __half2 a = __floats2half2_rn(v.x, v.y);
    __half2 b = __floats2half2_rn(v.z, v.w);
    out[t] = make_uint2(*(unsigned*)&a, *(unsigned*)&b);
}

// ---------------- fused gather (fp16 in, fp16/f32 out) -----------------------
// out = relu?(sbuf + mean_nbr(x)); fp16 h out (+fp16 concat copy) or f32 d_out
template<int F>
__global__ __launch_bounds__(TB) void gather_fused_h(
        const uint2* __restrict__ xh, const int* __restrict__ col,
        const int* __restrict__ rowptr, const float* __restrict__ sbuf,
        const f16* __restrict__ hcopyh, f16* __restrict__ outh,
        float* __restrict__ outf, int M, int ldout, int doRelu) {
    constexpr int C4 = F / 4;      // 8-byte chunks per row: 16 (F=64) or 8 (F=32)
    constexpr int ES = 64 / C4;    // edge slices per wave
    const int wave = threadIdx.x >> 6;
    const int lane = threadIdx.x & 63;
    const int node = blockIdx.x * (TB / 64) + wave;
    if (node >= M) return;
    const int c4 = lane & (C4 - 1);
    const int es = lane >> (F == 64 ? 4 : 3);

    const int s = rowptr[node], e = rowptr[node + 1];
    float ax = 0.f, ay = 0.f, az = 0.f, aw = 0.f;
    int j = s + es;
    for (; j + ES < e; j += 2 * ES) {
        int cs0 = col[j];
        int cs1 = col[j + ES];
        uint2 u0 = xh[(size_t)cs0 * C4 + c4];
        uint2 u1 = xh[(size_t)cs1 * C4 + c4];
        float2 f0 = __half22float2(*(__half2*)&u0.x);
        float2 f1 = __half22float2(*(__half2*)&u0.y);
        float2 g0 = __half22float2(*(__half2*)&u1.x);
        float2 g1 = __half22float2(*(__half2*)&u1.y);
        ax += f0.x + g0.x; ay += f0.y + g0.y;
        az += f1.x + g1.x; aw += f1.y + g1.y;
    }
    if (j < e) {
        int cs = col[j];
        uint2 u = xh[(size_t)cs * C4 + c4];
        float2 f0 = __half22float2(*(__half2*)&u.x);
        float2 f1 = __half22float2(*(__half2*)&u.y);
        ax += f0.x; ay += f0.y; az += f1.x; aw += f1.y;
    }
    #pragma unroll
    for (int d = C4; d < 64; d <<= 1) {
        ax += __shfl_xor(ax, d);
        ay += __shfl_xor(ay, d);
        az += __shfl_xor(az, d);
        aw += __shfl_xor(aw, d);
    }
    if (es == 0) {
        const float inv = 1.0f / fmaxf((float)(e - s), 1.0f);
        float4 v = make_float4(ax * inv, ay * inv, az * inv, aw * inv);
        if (sbuf) {
            float4 sv = *(const float4*)(sbuf + (size_t)node * F + 4 * c4);
            v.x += sv.x; v.y += sv.y; v.z += sv.z; v.w += sv.w;
        }
        if (doRelu) {
            v.x = fmaxf(v.x, 0.f); v.y = fmaxf(v.y, 0.f);
            v.z = fmaxf(v.z, 0.f); v.w = fmaxf(v.w, 0.f);
        }
        if (outh) {
            __half2 p0 = __floats2half2_rn(v.x, v.y);
            __half2 p1 = __floats2half2_rn(v.z, v.w);
            *(uint2*)(outh + (size_t)node * ldout + 4 * c4) =
                make_uint2(*(unsigned*)&p0, *(unsigned*)&p1);
            if (hcopyh) {   // concat: copy prev h (fp16) into upper half
                uint2 hv = *(const uint2*)(hcopyh + (size_t)node * F + 4 * c4);
                *(uint2*)(outh + (size_t)node * ldout + F + 4 * c4) = hv;
            }
        }
        if (outf)
            *(float4*)(outf + (size_t)node * ldout + 4 * c4) = v;
    }
}

// ---------------- MFMA dual-OUTPUT GEMM: Yh = fp16(A@Wn); S = A@Ws + b -------
// 4 waves x 2 row-tiles of 16 = 128 rows/block. W^T fp16 in LDS (padded rows).
template<int K, int N>
__global__ __launch_bounds__(TB) void gemm_mfma_dualout(
        const f16* __restrict__ Ah, const float* __restrict__ Wn,
        const float* __restrict__ Ws, const float* __restrict__ bias,
        f16* __restrict__ Yh, float* __restrict__ S, int M) {
    constexpr int KP = K + 8;      // padded k-stride (halves) -> conflict-free
    constexpr int NT = N / 16;     // n tiles per wave
    constexpr int KS = K / 32;     // k steps
    __shared__ f16 lwn[N * KP];
    __shared__ f16 lws[N * KP];
    const int tid = threadIdx.x;
    for (int idx = tid; idx < K * N; idx += TB) {
        int k = idx / N, n = idx - k * N;
        lwn[n * KP + k] = (f16)Wn[idx];
        lws[n * KP + k] = (f16)Ws[idx];
    }
    __syncthreads();

    const int lane = tid & 63;
    const int lr = lane & 15, lh = lane >> 4;
    const int rbase = blockIdx.x * 128 + (tid >> 6) * 32;
    const bool v0 = rbase < M, v1 = rbase + 16 < M;   // M % 16 == 0

    f32x4 accY[2][NT], accS[2][NT];
    const f32x4 z = {0.f, 0.f, 0.f, 0.f};
    #pragma unroll
    for (int r = 0; r < 2; ++r)
        #pragma unroll
        for (int t = 0; t < NT; ++t) { accY[r][t] = z; accS[r][t] = z; }

    for (int ks = 0; ks < KS; ++ks) {
        const int kb = ks * 32 + lh * 8;
        f16x8 a0 = {}, a1 = {};
        if (v0) a0 = *(const f16x8*)(Ah + (size_t)(rbase + lr) * K + kb);
        if (v1) a1 = *(const f16x8*)(Ah + (size_t)(rbase + 16 + lr) * K + kb);
        #pragma unroll
        for (int t = 0; t < NT; ++t) {
            f16x8 bn = *(const f16x8*)(&lwn[(t * 16 + lr) * KP + kb]);
            f16x8 bs = *(const f16x8*)(&lws[(t * 16 + lr) * KP + kb]);
            if (v0) { accY[0][t] = mfma16(a0, bn, accY[0][t]);
                      accS[0][t] = mfma16(a0, bs, accS[0][t]); }
            if (v1) { accY[1][t] = mfma16(a1, bn, accY[1][t]);
                      accS[1][t] = mfma16(a1, bs, accS[1][t]); }
        }
    }

    #pragma unroll
    for (int r = 0; r < 2; ++r) {
        const bool vr = r ? v1 : v0;
        if (vr) {
            const int rT = rbase + r * 16 + 4 * lh;   // D: row=(lane>>4)*4+reg
            #pragma unroll
            for (int t = 0; t < NT; ++t) {
                const int c = t * 16 + lr;            // D: col=lane&15
                const float bb = bias[c];
                #pragma unroll
                for (int g = 0; g < 4; ++g) {
                    const int row = rT + g;
                    S[(size_t)row * N + c] = accS[r][t][g] + bb;
                    Yh[(size_t)row * N + c] = (f16)accY[r][t][g];
                }
            }
        }
    }
}

// ---------------- MFMA dual-INPUT GEMM (layer 1): relu(A@Ws + A2@Wn + b) -----
template<int K, int N>
__global__ __launch_bounds__(TB) void gemm_mfma_dualin(
        const f16* __restrict__ Ah, const f16* __restrict__ A2h,
        const float* __restrict__ Ws, const float* __restrict__ Wn,
        const float* __restrict__ bias, f16* __restrict__ outh, int M) {
    constexpr int KP = K + 8;
    constexpr int NT = N / 16;
    constexpr int KS = K / 32;
    __shared__ f16 lws[N * KP];
    __shared__ f16 lwn[N * KP];
    const int tid = threadIdx.x;
    for (int idx = tid; idx < K * N; idx += TB) {
        int k = idx / N, n = idx - k * N;
        lws[n * KP + k] = (f16)Ws[idx];
        lwn[n * KP + k] = (f16)Wn[idx];
    }
    __syncthreads();

    const int lane = tid & 63;
    const int lr = lane & 15, lh = lane >> 4;
    const int rbase = blockIdx.x * 128 + (tid >> 6) * 32;
    const bool v0 = rbase < M, v1 = rbase + 16 < M;

    f32x4 acc[2][NT];
    const f32x4 z = {0.f, 0.f, 0.f, 0.f};
    #pragma unroll
    for (int r = 0; r < 2; ++r)
        #pragma unroll
        for (int t = 0; t < NT; ++t) acc[r][t] = z;

    for (int ks = 0; ks < KS; ++ks) {
        const int kb = ks * 32 + lh * 8;
        f16x8 a0 = {}, a1 = {}, g0 = {}, g1 = {};
        if (v0) { a0 = *(const f16x8*)(Ah  + (size_t)(rbase + lr) * K + kb);
                  g0 = *(const f16x8*)(A2h + (size_t)(rbase + lr) * K + kb); }
        if (v1) { a1 = *(const f16x8*)(Ah  + (size_t)(rbase + 16 + lr) * K + kb);
                  g1 = *(const f16x8*)(A2h + (size_t)(rbase + 16 + lr) * K + kb); }
        #pragma unroll
        for (int t = 0; t < NT; ++t) {
            f16x8 bs = *(const f16x8*)(&lws[(t * 16 + lr) * KP + kb]);
            f16x8 bn = *(const f16x8*)(&lwn[(t * 16 + lr) * KP + kb]);
            if (v0) { acc[0][t] = mfma16(a0, bs, acc[0][t]);
                      acc[0][t] = mfma16(g0, bn, acc[0][t]); }
            if (v1) { acc[1][t] = mfma16(a1, bs, acc[1][t]);
                      acc[1][t] = mfma16(g1, bn, acc[1][t]); }
        }
    }

    #pragma unroll
    for (int r = 0; r < 2; ++r) {
        const bool vr = r ? v1 : v0;
        if (vr) {
            const int rT = rbase + r * 16 + 4 * lh;
            #pragma unroll
            for (int t = 0; t < NT; ++t) {
                const int c = t * 16 + lr;
                const float bb = bias[c];
                #pragma unroll
                for (int g = 0; g < 4; ++g) {
                    const int row = rT + g;
                    float v = acc[r][t][g] + bb;
                    outh[(size_t)row * N + c] = (f16)fmaxf(v, 0.f);
                }
            }
        }
    }
}

// ---------------- host orchestration ----------------------------------------
static inline int cdiv_i(long long a, int b) { return (int)((a + b - 1) / b); }

template<int F>
static void launch_gather(const f16* xh, const int* col, const int* rowptr,
                          const float* sbuf, const f16* hcopyh,
                          f16* outh, float* outf, int M, int ldout, int relu,
                          hipStream_t stream) {
    hipLaunchKernelGGL((gather_fused_h<F>), dim3(cdiv_i(M, TB / 64)), dim3(TB), 0, stream,
                       (const uint2*)xh, col, rowptr, sbuf, hcopyh, outh, outf,
                       M, ldout, relu);
}

extern "C" void kernel_launch(void* const* d_in, const int* in_sizes, int n_in,
                              void* d_out, int out_size, void* d_ws, size_t ws_size,
                              hipStream_t stream) {
    const float* in_feat = (const float*)d_in[0];
    const void* src = d_in[1];
    const void* dst = d_in[2];
    const float* Ws1 = (const float*)d_in[3];  const float* Wn1 = (const float*)d_in[4];  const float* b1 = (const float*)d_in[5];
    const float* Ws2 = (const float*)d_in[6];  const float* Wn2 = (const float*)d_in[7];  const float* b2 = (const float*)d_in[8];
    const float* Ws3 = (const float*)d_in[9];  const float* Wn3 = (const float*)d_in[10]; const float* b3 = (const float*)d_in[11];
    const float* Ws4 = (const float*)d_in[12]; const float* Wn4 = (const float*)d_in[13]; const float* b4 = (const float*)d_in[14];
    const float* Ws5 = (const float*)d_in[15]; const float* Wn5 = (const float*)d_in[16]; const float* b5 = (const float*)d_in[17];
    const float* Ws6 = (const float*)d_in[18]; const float* Wn6 = (const float*)d_in[19]; const float* b6 = (const float*)d_in[20];

    const int M  = in_sizes[0] / 64;   // 100000 nodes
    const int nE = in_sizes[1];        // 1600000 edges
    const int nBk = cdiv_i(M, 256);    // coarse buckets (391)
    const int EC  = cdiv_i(nE, NBLK_P);

    // workspace layout
    float* sbuf = (float*)d_ws;                   // M*64 f32 (S; aliased ebuf in build)
    f16* Yh   = (f16*)(sbuf + (size_t)M * 64);    // M*64
    f16* P1h  = Yh + (size_t)M * 64;              // M*128
    f16* P2h  = P1h + (size_t)M * 128;            // M*64
    f16* P3h  = P2h + (size_t)M * 64;             // M*32
    f16* aggh = P3h + (size_t)M * 32;             // M*64
    f16* xh   = aggh + (size_t)M * 64;            // M*64
    int* rowptr = (int*)(xh + (size_t)M * 64);    // M+1
    int* col    = rowptr + (M + 1);               // nE
    int* T      = col + nE;                       // NBK
    int* Bbase  = T + NBK;                        // NBK
    int* flag   = Bbase + NBK;                    // 1
    int* H      = flag + 1;                       // NBLK_P * NBK
    int2* ebuf  = (int2*)sbuf;                    // nE int2 (build only)

    // ---- CSR build (counting sort; no global atomics)
    hipLaunchKernelGGL(detect_idx_kernel, dim3(1), dim3(TB), 0, stream,
                       (const int*)src, (const int*)dst, nE, flag);
    hipLaunchKernelGGL(passA_kernel, dim3(NBLK_P), dim3(TB), 0, stream,
                       dst, flag, H, nE, EC, nBk);
    hipLaunchKernelGGL(colscan_kernel, dim3(cdiv_i(nBk, TB)), dim3(TB), 0, stream,
                       H, T, nBk);
    hipLaunchKernelGGL(bucket_scan_kernel, dim3(1), dim3(512), 0, stream, T, Bbase, nBk);
    hipLaunchKernelGGL(passB_kernel, dim3(NBLK_P), dim3(TB), 0, stream,
                       src, dst, flag, H, Bbase, ebuf, nE, EC, nBk);
    hipLaunchKernelGGL(bucket_build_kernel, dim3(nBk), dim3(TB), 0, stream,
                       ebuf, Bbase, rowptr, col, M, nBk, nE);

    // fp16 copy of in_feat
    hipLaunchKernelGGL(tofp16_kernel, dim3(cdiv_i((long long)M * 16, TB)), dim3(TB), 0, stream,
                       (const float4*)in_feat, (uint2*)xh, M * 16);

    const int mblocks = cdiv_i(M, 128);   // MFMA GEMM grid (128 rows/block)

    // ---- layer 1: 64 -> 128, relu: h1 = relu(x@Ws1 + mean(x)@Wn1 + b1)
    launch_gather<64>(xh, col, rowptr, nullptr, nullptr, aggh, nullptr, M, 64, 0, stream);
    hipLaunchKernelGGL((gemm_mfma_dualin<64, 128>), dim3(mblocks), dim3(TB), 0, stream,
                       xh, aggh, Ws1, Wn1, b1, P1h, M);

    // ---- layer 2: 128 -> 64, relu
    hipLaunchKernelGGL((gemm_mfma_dualout<128, 64>), dim3(mblocks), dim3(TB), 0, stream,
                       P1h, Wn2, Ws2, b2, Yh, sbuf, M);
    launch_gather<64>(Yh, col, rowptr, sbuf, nullptr, P2h, nullptr, M, 64, 1, stream);

    // ---- layer 3: 64 -> 32, relu
    hipLaunchKernelGGL((gemm_mfma_dualout<64, 32>), dim3(mblocks), dim3(TB), 0, stream,
                       P2h, Wn3, Ws3, b3, Yh, sbuf, M);
    launch_gather<32>(Yh, col, rowptr, sbuf, nullptr, P3h, nullptr, M, 32, 1, stream);

    // ---- layer 4: 32 -> 32, relu, concat h3 -> h4 (64 wide)
    hipLaunchKernelGGL((gemm_mfma_dualout<32, 32>), dim3(mblocks), dim3(TB), 0, stream,
                       P3h, Wn4, Ws4, b4, Yh, sbuf, M);
    launch_gather<32>(Yh, col, rowptr, sbuf, P3h, P2h, nullptr, M, 64, 1, stream);

    // ---- layer 5: 64 -> 64, relu, concat h4 -> h5 (128 wide)
    hipLaunchKernelGGL((gemm_mfma_dualout<64, 64>), dim3(mblocks), dim3(TB), 0, stream,
                       P2h, Wn5, Ws5, b5, Yh, sbuf, M);
    launch_gather<64>(Yh, col, rowptr, sbuf, P2h, P1h, nullptr, M, 128, 1, stream);

    // ---- layer 6: 128 -> 64, no relu, f32 out to d_out
    hipLaunchKernelGGL((gemm_mfma_dualout<128, 64>), dim3(mblocks), dim3(TB), 0, stream,
                       P1h, Wn6, Ws6, b6, Yh, sbuf, M);
    launch_gather<64>(Yh, col, rowptr, sbuf, nullptr, nullptr, (float*)d_out, M, 64, 0, stream);
}